// Round 9
// baseline (346.282 us; speedup 1.0000x reference)
//
#include <hip/hip_runtime.h>
#include <cstdint>
#include <cstddef>

// DCNv2 x2 (B=2, C=O=256, H=W=96, k=3), fully fused per layer.
// R20: session-wide finding: every kernel costs ~2500-3500cy per
// barrier-synchronized interval at ~9 waves/CU, nearly independent of
// content (v2: 36x2560; R16-control: 36x3550; offconv: 36x3250). Lever:
// FEWER INTERVALS. dfconv v3 = v2 structure with K=128/round -> 18
// barriers (was 36): A-DMA 8KB/wave/round (single wave-private buf,
// overwrite-after-own-read), 2 B panels/round (each thread stages ONE
// cell of its panel p=tid>>8), 16 MFMA/wave/round, one __syncthreads.
// LDS 88.8KB (1 blk/CU - shown costless in R17/R19). launch_bounds(512,2)
// eliminates spill risk (R18 lesson). offconv/transpose/preps unchanged.
// k' = kk*256 + c. XCD swizzle: blockIdx%8 = XCD.

#define KTOT 2304
#define PXB  9216

typedef __attribute__((ext_vector_type(8))) short bf16x8;
typedef __attribute__((ext_vector_type(4))) float f32x4;

static __device__ __forceinline__ unsigned short f2bf(float f) {
    union { float f; unsigned int u; } v; v.f = f;
    unsigned int r = (v.u + 0x7FFFu + ((v.u >> 16) & 1u)) >> 16;
    return (unsigned short)r;
}
static __device__ __forceinline__ float bf2f(unsigned short h) {
    union { unsigned int u; float f; } v; v.u = ((unsigned int)h) << 16;
    return v.f;
}
// unpack 8 bf16 (uint4) -> 8 fp32; 1 bit-op per element
static __device__ __forceinline__ void unpack8(uint4 u, float* f) {
    union { unsigned int u; float f; } t;
    t.u = u.x << 16;         f[0] = t.f;
    t.u = u.x & 0xffff0000u; f[1] = t.f;
    t.u = u.y << 16;         f[2] = t.f;
    t.u = u.y & 0xffff0000u; f[3] = t.f;
    t.u = u.z << 16;         f[4] = t.f;
    t.u = u.z & 0xffff0000u; f[5] = t.f;
    t.u = u.w << 16;         f[6] = t.f;
    t.u = u.w & 0xffff0000u; f[7] = t.f;
}

// ---------------------------------------------------------------------------
// NCHW -> NHWC transpose, hi/lo bf16 outputs
// ---------------------------------------------------------------------------
__global__ __launch_bounds__(256) void transpose_kernel(const float* __restrict__ in,
                                                        unsigned short* __restrict__ outH,
                                                        unsigned short* __restrict__ outL) {
    __shared__ float tile[64][65];
    const int hw0 = blockIdx.x * 64;
    const int c0  = blockIdx.y * 64;
    const int b   = blockIdx.z;
    const int lx  = threadIdx.x & 63;
    const int ly  = threadIdx.x >> 6;
#pragma unroll
    for (int i = 0; i < 16; ++i) {
        int cl = ly + i * 4;
        tile[cl][lx] = in[(size_t)(b * 256 + c0 + cl) * PXB + hw0 + lx];
    }
    __syncthreads();
#pragma unroll
    for (int i = 0; i < 16; ++i) {
        int hwl = ly + i * 4;
        float v = tile[lx][hwl];
        size_t oi = ((size_t)b * PXB + hw0 + hwl) * 256 + c0 + lx;
        unsigned short hi = f2bf(v);
        outH[oi] = hi;
        outL[oi] = f2bf(v - bf2f(hi));
    }
}

// ---------------------------------------------------------------------------
// Main weight prep: w[o][c][kk] fp32 -> wA[o][k'=kk*256+c] bf16
// ---------------------------------------------------------------------------
__global__ __launch_bounds__(256) void prep_w_kernel(const float* __restrict__ w,
                                                     unsigned short* __restrict__ wA) {
    int idx = blockIdx.x * 256 + threadIdx.x;   // 256*2304
    int o = idx / KTOT;
    int k = idx - o * KTOT;
    int kk = k >> 8;
    int c  = k & 255;
    wA[idx] = f2bf(w[o * KTOT + c * 9 + kk]);
}

// ---------------------------------------------------------------------------
// Offset weight prep (split): rows 27..32 zero. hi = bf16(w), lo = bf16(w-hi).
// ---------------------------------------------------------------------------
__global__ __launch_bounds__(256) void prep_woff_kernel(const float* __restrict__ w,
                                                        unsigned short* __restrict__ wH,
                                                        unsigned short* __restrict__ wL) {
    int idx = blockIdx.x * 256 + threadIdx.x;   // 32*2304
    int o = idx / KTOT;
    int k = idx - o * KTOT;
    int kk = k >> 8;
    int c  = k & 255;
    float f = (o < 27) ? w[o * KTOT + c * 9 + kk] : 0.0f;
    unsigned short hi = f2bf(f);
    wH[idx] = hi;
    wL[idx] = f2bf(f - bf2f(hi));
}

// ---------------------------------------------------------------------------
// Fused offset conv: M=32(27) x N=64px x K=2304, split-bf16 3-term. (R12)
// ---------------------------------------------------------------------------
__global__ __launch_bounds__(512) void offconv_fused(const unsigned short* __restrict__ xH,
                                                     const unsigned short* __restrict__ xL,
                                                     const unsigned short* __restrict__ AH,
                                                     const unsigned short* __restrict__ AL,
                                                     const float* __restrict__ bias,
                                                     float* __restrict__ om) {
    __shared__ __attribute__((aligned(16))) unsigned short AsH[2][32 * 72];
    __shared__ __attribute__((aligned(16))) unsigned short AsL[2][32 * 72];
    __shared__ __attribute__((aligned(16))) unsigned short BsH[2][64 * 72];
    __shared__ __attribute__((aligned(16))) unsigned short BsL[2][64 * 72];

    const int tid  = threadIdx.x;
    const int kg   = tid >> 8;
    const int tl   = tid & 255;
    const int lane = tid & 63;
    const int wq   = (tid >> 6) & 3;
    const int quad = lane >> 4, l16 = lane & 15;
    const int g    = blockIdx.x;            // 288
    const int nb   = (g & 7) * 36 + (g >> 3);
    const int n0   = nb * 64;
    const int b    = n0 / PXB;
    const int hw0  = n0 - b * PXB;

    f32x4 acc[2];
#pragma unroll
    for (int mt = 0; mt < 2; ++mt) acc[mt] = (f32x4)0.0f;

    const int arow = tl >> 3, akg = tl & 7;

    uint4 pAH, pAL, pBH0, pBL0, pBH1, pBL1;
    auto pf = [&](int it) {
        const int kt = kg * 18 + it;
        const int kk = kt >> 2, c0 = (kt & 3) * 64;
        const int dy = kk / 3 - 1, dx = kk - (kk / 3) * 3 - 1;
        size_t ai = (size_t)arow * KTOT + kt * 64 + akg * 8;
        pAH = *(const uint4*)&AH[ai];
        pAL = *(const uint4*)&AL[ai];
#pragma unroll
        for (int i = 0; i < 2; ++i) {
            int task = i * 256 + tl;
            int px = task >> 3, cg = task & 7;
            int hw = hw0 + px;
            int h = hw / 96, w = hw - h * 96;
            int y = h + dy, x = w + dx;
            uint4 hv = make_uint4(0u, 0u, 0u, 0u), lv = make_uint4(0u, 0u, 0u, 0u);
            if (((unsigned)y < 96u) && ((unsigned)x < 96u)) {
                size_t bi = ((size_t)b * PXB + y * 96 + x) * 256 + c0 + cg * 8;
                hv = *(const uint4*)&xH[bi];
                lv = *(const uint4*)&xL[bi];
            }
            if (i == 0) { pBH0 = hv; pBL0 = lv; } else { pBH1 = hv; pBL1 = lv; }
        }
    };
    pf(0);

    for (int it = 0; it < 18; ++it) {
        __syncthreads();
        *(uint4*)&AsH[kg][arow * 72 + akg * 8] = pAH;
        *(uint4*)&AsL[kg][arow * 72 + akg * 8] = pAL;
        {
            int px = tl >> 3, cg = tl & 7;
            *(uint4*)&BsH[kg][px * 72 + cg * 8] = pBH0;
            *(uint4*)&BsL[kg][px * 72 + cg * 8] = pBL0;
        }
        {
            int task = 256 + tl;
            int px = task >> 3, cg = task & 7;
            *(uint4*)&BsH[kg][px * 72 + cg * 8] = pBH1;
            *(uint4*)&BsL[kg][px * 72 + cg * 8] = pBL1;
        }
        if (it < 17) pf(it + 1);
        __syncthreads();
#pragma unroll
        for (int ks = 0; ks < 2; ++ks) {
            bf16x8 ah[2], al[2], bh, bl;
#pragma unroll
            for (int mt = 0; mt < 2; ++mt) {
                ah[mt] = *(const bf16x8*)&AsH[kg][(mt * 16 + l16) * 72 + ks * 32 + quad * 8];
                al[mt] = *(const bf16x8*)&AsL[kg][(mt * 16 + l16) * 72 + ks * 32 + quad * 8];
            }
            bh = *(const bf16x8*)&BsH[kg][(wq * 16 + l16) * 72 + ks * 32 + quad * 8];
            bl = *(const bf16x8*)&BsL[kg][(wq * 16 + l16) * 72 + ks * 32 + quad * 8];
#pragma unroll
            for (int mt = 0; mt < 2; ++mt) {
                acc[mt] = __builtin_amdgcn_mfma_f32_16x16x32_bf16(ah[mt], bh, acc[mt], 0, 0, 0);
                acc[mt] = __builtin_amdgcn_mfma_f32_16x16x32_bf16(ah[mt], bl, acc[mt], 0, 0, 0);
                acc[mt] = __builtin_amdgcn_mfma_f32_16x16x32_bf16(al[mt], bh, acc[mt], 0, 0, 0);
            }
        }
    }

    float* red = (float*)BsH;
    __syncthreads();
    if (kg == 1) {
#pragma unroll
        for (int mt = 0; mt < 2; ++mt)
#pragma unroll
            for (int r = 0; r < 4; ++r)
                red[wq * 512 + mt * 256 + quad * 64 + r * 16 + l16] = acc[mt][r];
    }
    __syncthreads();
    if (kg == 0) {
#pragma unroll
        for (int mt = 0; mt < 2; ++mt)
#pragma unroll
            for (int r = 0; r < 4; ++r) {
                float v = acc[mt][r] + red[wq * 512 + mt * 256 + quad * 64 + r * 16 + l16];
                int m = mt * 16 + quad * 4 + r;
                int n = wq * 16 + l16;
                if (m < 27)
                    om[(size_t)(b * 27 + m) * PXB + hw0 + n] = v + bias[m];
            }
    }
}

// ---------------------------------------------------------------------------
// Fused deformable conv v3 (both layers): M=256 x N=32, 18 rounds x K=128.
// A: single wave-private LDS buf (8KB/wave), global_load_lds DMA, XOR-16
// source swizzle (slot t of row r holds granule t^(r&15)); overwrite only
// after own ds_reads (lgkmcnt(0)+sched_barrier). B: 2 panels (p=tid>>8) x
// double-buffered; each thread stages ONE cell/round (corner prefetch at
// round top, interp after MFMA). ONE __syncthreads per round (drains DMA).
// out_mode 0: NCHW fp32. out_mode 1: NHWC hi/lo bf16 (outH/outL).
// ---------------------------------------------------------------------------
__global__ __launch_bounds__(512, 2) void dfconv_v3(const unsigned short* __restrict__ xB,
                                                    const float* __restrict__ om,
                                                    const unsigned short* __restrict__ A,
                                                    float* __restrict__ out,
                                                    unsigned short* __restrict__ outH,
                                                    unsigned short* __restrict__ outL,
                                                    int out_mode) {
    // arena: Abuf [8 waves][8192]B @0 (65536) | Bs [2 dbuf][2 panel][4608]B
    //        @65536 (18432) | goff @83968 (2304) | gwt @86272 (4608) = 90880
    __shared__ __attribute__((aligned(16))) char smem[90880];
    unsigned short* BsD  = (unsigned short*)(smem + 65536);   // ushort units
    unsigned short* goff = (unsigned short*)(smem + 83968);
    float*          gwt  = (float*)(smem + 86272);

    const int tid  = threadIdx.x;
    const int wv   = tid >> 6;
    const int lane = tid & 63;
    const int quad = lane >> 4, l16 = lane & 15;
    const int g    = blockIdx.x;            // 576
    const int nb   = (g & 7) * 72 + (g >> 3);
    const int n0   = nb * 32;
    const int b    = n0 / PXB;
    const int hw0  = n0 - b * PXB;

    // ---- geometry: 32 px x 9 taps ----
    if (tid < 288) {
        int task = tid;
        int px = task / 9;
        int kk = task - px * 9;
        int hw = hw0 + px;
        int h = hw / 96, w = hw - h * 96;
        const float* omp = om + (size_t)b * 27 * PXB + hw;
        float dyv = omp[(size_t)(2 * kk) * PXB];
        float dxv = omp[(size_t)(2 * kk + 1) * PXB];
        float mv  = omp[(size_t)(18 + kk) * PXB];
        float mk  = 1.0f / (1.0f + __expf(-mv));

        float ys = (float)(h + (kk / 3) - 1) + dyv;
        float xs = (float)(w + (kk - (kk / 3) * 3) - 1) + dxv;
        float fy = floorf(ys), fx = floorf(xs);
        int iy = (int)fy, ix = (int)fx;
        float wy1 = ys - fy, wx1 = xs - fx;
        float wy0 = 1.0f - wy1, wx0 = 1.0f - wx1;
        bool yv0 = (unsigned)iy < 96u, yv1 = (unsigned)(iy + 1) < 96u;
        bool xv0 = (unsigned)ix < 96u, xv1 = (unsigned)(ix + 1) < 96u;
        int y0 = min(max(iy, 0), 95),     y1 = min(max(iy + 1, 0), 95);
        int x0 = min(max(ix, 0), 95),     x1 = min(max(ix + 1, 0), 95);
        int gg = task * 4;
        goff[gg + 0] = (unsigned short)(y0 * 96 + x0);
        goff[gg + 1] = (unsigned short)(y0 * 96 + x1);
        goff[gg + 2] = (unsigned short)(y1 * 96 + x0);
        goff[gg + 3] = (unsigned short)(y1 * 96 + x1);
        gwt[gg + 0] = (yv0 && xv0) ? mk * wy0 * wx0 : 0.0f;
        gwt[gg + 1] = (yv0 && xv1) ? mk * wy0 * wx1 : 0.0f;
        gwt[gg + 2] = (yv1 && xv0) ? mk * wy1 * wx0 : 0.0f;
        gwt[gg + 3] = (yv1 && xv1) ? mk * wy1 * wx1 : 0.0f;
    }
    __syncthreads();

    // ---- staging roles: panel p = tid>>8, one cell per thread per round ----
    const int p  = tid >> 8;                // panel 0/1 -> kt = 2r + p
    const int px = (tid & 255) >> 3;        // 0..31
    const int cg = tid & 7;                 // channel group
    const unsigned short* xbase = xB + (size_t)b * PXB * 256 + cg * 8;

    f32x4 acc[2][2];
#pragma unroll
    for (int mt = 0; mt < 2; ++mt)
#pragma unroll
        for (int nt = 0; nt < 2; ++nt) acc[mt][nt] = (f32x4)0.0f;

    // A DMA: 8 shots of 1KB per wave per round. Shot s = rows s*4..s*4+3.
    // lane -> (row_in_shot = lane>>4, slot = lane&15); source granule
    // g = slot ^ (row&15) so LDS slot t of row r holds granule t^(r&15).
    const int rsh = lane >> 4;               // row in shot
    const int slt = lane & 15;               // slot
    auto dmaA = [&](int r) {
#pragma unroll
        for (int s = 0; s < 8; ++s) {
            const int row = s * 4 + rsh;
            const int gs  = slt ^ (row & 15);
            const unsigned short* src =
                A + (size_t)(wv * 32 + row) * KTOT + r * 128 + gs * 8;
            char* dst = smem + wv * 8192 + s * 1024;
            __builtin_amdgcn_global_load_lds(
                (const __attribute__((address_space(1))) unsigned int*)src,
                (__attribute__((address_space(3))) unsigned int*)dst, 16, 0, 0);
        }
    };

    // ---- prologue: A(0) DMA; interp cells kt=p (both panels) -> dbuf0 ----
    dmaA(0);
    {
        const int kt = p, tap = kt >> 2, c0 = (kt & 3) * 64;
        int gg = (px * 9 + tap) * 4;
        ushort4 o4 = *(const ushort4*)&goff[gg];
        float4 wt = *(const float4*)&gwt[gg];
        const unsigned short* cb = xbase + c0;
        uint4 u0 = *(const uint4*)(cb + (size_t)o4.x * 256);
        uint4 u1 = *(const uint4*)(cb + (size_t)o4.y * 256);
        uint4 u2 = *(const uint4*)(cb + (size_t)o4.z * 256);
        uint4 u3 = *(const uint4*)(cb + (size_t)o4.w * 256);
        float f0[8], f1[8], f2[8], f3[8];
        unpack8(u0, f0); unpack8(u1, f1); unpack8(u2, f2); unpack8(u3, f3);
        unsigned short res[8];
#pragma unroll
        for (int j = 0; j < 8; ++j)
            res[j] = f2bf(wt.x * f0[j] + wt.y * f1[j] + wt.z * f2[j] + wt.w * f3[j]);
        *(uint4*)&BsD[p * 2304 + px * 72 + cg * 8] = *(uint4*)res;
    }
    __syncthreads();    // A(0) drained, B(0) visible

    // ---- main loop: 18 rounds, ONE barrier each ----
    for (int r = 0; r < 18; ++r) {
        const int cur = r & 1;

        // 1. corner prefetch for round r+1 (this thread's panel cell)
        uint4 cc0, cc1, cc2, cc3; float4 wt;
        if (r < 17) {
            const int ktn = 2 * (r + 1) + p, tap = ktn >> 2, c0 = (ktn & 3) * 64;
            int gg = (px * 9 + tap) * 4;
            ushort4 o4 = *(const ushort4*)&goff[gg];
            wt = *(const float4*)&gwt[gg];
            const unsigned short* cb = xbase + c0;
            cc0 = *(const uint4*)(cb + (size_t)o4.x * 256);
            cc1 = *(const uint4*)(cb + (size_t)o4.y * 256);
            cc2 = *(const uint4*)(cb + (size_t)o4.z * 256);
            cc3 = *(const uint4*)(cb + (size_t)o4.w * 256);
        }

        // 2. A-fragments: LDS -> regs (wave-private region, XOR-16 layout)
        bf16x8 af[2][2][2];   // [pp][ks][mt]
        {
            const char* Ac = smem + wv * 8192;
#pragma unroll
            for (int pp = 0; pp < 2; ++pp)
#pragma unroll
                for (int ks = 0; ks < 2; ++ks)
#pragma unroll
                    for (int mt = 0; mt < 2; ++mt) {
                        const int row = mt * 16 + l16;
                        const int gw  = pp * 8 + ks * 4 + quad;
                        af[pp][ks][mt] = *(const bf16x8*)(Ac + row * 256
                                                          + ((gw ^ (row & 15)) * 16));
                    }
        }
        // A reads complete before overwrite; fence per rule #18
        asm volatile("s_waitcnt lgkmcnt(0)" ::: "memory");
        __builtin_amdgcn_sched_barrier(0);

        // 3. DMA A(r+1) into the SAME wave-private region (safe post-read)
        if (r < 17) dmaA(r + 1);

        // 4. MFMA: 2 panels x 2 ks x (2mt x 2nt) = 16
#pragma unroll
        for (int pp = 0; pp < 2; ++pp) {
            const unsigned short* Br = BsD + (cur * 2 + pp) * 2304;
#pragma unroll
            for (int ks = 0; ks < 2; ++ks) {
                bf16x8 b0 = *(const bf16x8*)&Br[l16 * 72 + ks * 32 + quad * 8];
                bf16x8 b1 = *(const bf16x8*)&Br[(16 + l16) * 72 + ks * 32 + quad * 8];
                acc[0][0] = __builtin_amdgcn_mfma_f32_16x16x32_bf16(af[pp][ks][0], b0, acc[0][0], 0, 0, 0);
                acc[0][1] = __builtin_amdgcn_mfma_f32_16x16x32_bf16(af[pp][ks][0], b1, acc[0][1], 0, 0, 0);
                acc[1][0] = __builtin_amdgcn_mfma_f32_16x16x32_bf16(af[pp][ks][1], b0, acc[1][0], 0, 0, 0);
                acc[1][1] = __builtin_amdgcn_mfma_f32_16x16x32_bf16(af[pp][ks][1], b1, acc[1][1], 0, 0, 0);
            }
        }

        // 5. interp prefetched corners -> other dbuf
        if (r < 17) {
            unsigned short* Bw = BsD + ((cur ^ 1) * 2 + p) * 2304;
            float f0[8], f1[8], f2[8], f3[8];
            unpack8(cc0, f0); unpack8(cc1, f1); unpack8(cc2, f2); unpack8(cc3, f3);
            unsigned short res[8];
#pragma unroll
            for (int j = 0; j < 8; ++j)
                res[j] = f2bf(wt.x * f0[j] + wt.y * f1[j] + wt.z * f2[j] + wt.w * f3[j]);
            *(uint4*)&Bw[px * 72 + cg * 8] = *(uint4*)res;
        }

        __syncthreads();    // DMA drained (A(r+1) ready), B(next) visible
    }

    // ---- epilogues: tileS aliases smem ----
    float* tileS = (float*)smem;
    if (out_mode == 0) {
        // NCHW out[b][m][hw0..+31]: 2 passes of 128 m; tileS[128][36]
#pragma unroll
        for (int pass = 0; pass < 2; ++pass) {
            if ((wv >> 2) == pass) {
#pragma unroll
                for (int mt = 0; mt < 2; ++mt)
#pragma unroll
                    for (int nt = 0; nt < 2; ++nt)
#pragma unroll
                        for (int rr = 0; rr < 4; ++rr) {
                            int ml = (wv & 3) * 32 + mt * 16 + quad * 4 + rr;
                            int n  = nt * 16 + l16;
                            tileS[ml * 36 + n] = fmaxf(acc[mt][nt][rr], 0.0f);
                        }
            }
            __syncthreads();
#pragma unroll
            for (int j = 0; j < 2; ++j) {
                int idx = j * 512 + tid;
                int row = idx >> 3, q = idx & 7;
                *(float4*)&out[(size_t)(b * 256 + pass * 128 + row) * PXB + hw0 + q * 4] =
                    *(const float4*)&tileS[row * 36 + q * 4];
            }
            __syncthreads();
        }
    } else {
        // NHWC hi/lo bf16 (outH/outL): 2 passes of 16 px; tileS[16][264]
#pragma unroll
        for (int pass = 0; pass < 2; ++pass) {
#pragma unroll
            for (int mt = 0; mt < 2; ++mt) {
                f32x4 v = acc[mt][pass];
                v[0] = fmaxf(v[0], 0.f); v[1] = fmaxf(v[1], 0.f);
                v[2] = fmaxf(v[2], 0.f); v[3] = fmaxf(v[3], 0.f);
                *(f32x4*)&tileS[l16 * 264 + wv * 32 + mt * 16 + quad * 4] = v;
            }
            __syncthreads();
#pragma unroll
            for (int j = 0; j < 2; ++j) {
                int idx = j * 512 + tid;
                int pxl = idx >> 6, ln = idx & 63;
                float4 v = *(const float4*)&tileS[pxl * 264 + ln * 4];
                size_t oi = ((size_t)b * PXB + hw0 + pass * 16 + pxl) * 256 + ln * 4;
                unsigned short hv[4], lv[4];
#pragma unroll
                for (int e = 0; e < 4; ++e) {
                    float fe = (e == 0) ? v.x : (e == 1) ? v.y : (e == 2) ? v.z : v.w;
                    hv[e] = f2bf(fe);
                    lv[e] = f2bf(fe - bf2f(hv[e]));
                }
                *(ushort4*)&outH[oi] = *(ushort4*)hv;
                *(ushort4*)&outL[oi] = *(ushort4*)lv;
            }
            __syncthreads();
        }
    }
}

// ---------------------------------------------------------------------------
extern "C" void kernel_launch(void* const* d_in, const int* in_sizes, int n_in,
                              void* d_out, int out_size, void* d_ws, size_t ws_size,
                              hipStream_t stream) {
    const float* x     = (const float*)d_in[0];
    const float* woff0 = (const float*)d_in[1];
    const float* boff0 = (const float*)d_in[2];
    const float* w0    = (const float*)d_in[3];
    const float* woff1 = (const float*)d_in[4];
    const float* boff1 = (const float*)d_in[5];
    const float* w1    = (const float*)d_in[6];
    float* out = (float*)d_out;

    char* p = (char*)d_ws;
    float* om  = (float*)p;  p += (size_t)2 * 27 * PXB * 4;               // 2.0 MB
    unsigned short* xh  = (unsigned short*)p; p += (size_t)2 * 256 * PXB * 2;  // 9.4 MB
    unsigned short* xl  = (unsigned short*)p; p += (size_t)2 * 256 * PXB * 2;  // 9.4 MB
    unsigned short* h1h = (unsigned short*)p; p += (size_t)2 * 256 * PXB * 2;  // 9.4 MB
    unsigned short* h1l = (unsigned short*)p; p += (size_t)2 * 256 * PXB * 2;  // 9.4 MB
    unsigned short* wA0 = (unsigned short*)p; p += (size_t)256 * KTOT * 2;
    unsigned short* wA1 = (unsigned short*)p; p += (size_t)256 * KTOT * 2;
    unsigned short* wH0 = (unsigned short*)p; p += (size_t)32 * KTOT * 2;
    unsigned short* wL0 = (unsigned short*)p; p += (size_t)32 * KTOT * 2;
    unsigned short* wH1 = (unsigned short*)p; p += (size_t)32 * KTOT * 2;
    unsigned short* wL1 = (unsigned short*)p; p += (size_t)32 * KTOT * 2;

    hipLaunchKernelGGL(transpose_kernel, dim3(PXB / 64, 4, 2), dim3(256), 0, stream, x, xh, xl);
    hipLaunchKernelGGL(prep_w_kernel, dim3(256 * KTOT / 256), dim3(256), 0, stream, w0, wA0);
    hipLaunchKernelGGL(prep_w_kernel, dim3(256 * KTOT / 256), dim3(256), 0, stream, w1, wA1);
    hipLaunchKernelGGL(prep_woff_kernel, dim3(32 * KTOT / 256), dim3(256), 0, stream, woff0, wH0, wL0);
    hipLaunchKernelGGL(prep_woff_kernel, dim3(32 * KTOT / 256), dim3(256), 0, stream, woff1, wH1, wL1);

    // Layer 0: x -> h1 (NHWC hi/lo bf16)
    hipLaunchKernelGGL(offconv_fused, dim3(288), dim3(512), 0, stream, xh, xl, wH0, wL0, boff0, om);
    hipLaunchKernelGGL(dfconv_v3, dim3(576), dim3(512), 0, stream, xh, om, wA0,
                       (float*)nullptr, h1h, h1l, 1);

    // Layer 1: h1 -> out (NCHW fp32)
    hipLaunchKernelGGL(offconv_fused, dim3(288), dim3(512), 0, stream, h1h, h1l, wH1, wL1, boff1, om);
    hipLaunchKernelGGL(dfconv_v3, dim3(576), dim3(512), 0, stream, h1h, om, wA1,
                       out, (unsigned short*)nullptr, (unsigned short*)nullptr, 0);
}

// Round 10
// 316.432 us; speedup vs baseline: 1.0943x; 1.0943x over previous
//
#include <hip/hip_runtime.h>
#include <cstdint>
#include <cstddef>

// DCNv2 x2 (B=2, C=O=256, H=W=96, k=3), fully fused per layer.
// R21: invariant across all structures: per-CU L2 read rate ~16-21 B/cy
// (latency x MLP bound). Time ~ bytes/CU / 20B/cy. Lever: amortize A over
// 2x the pixels. dfconv v4 = v2's EXACT round structure (wave-private A-DMA
// single-buffer, corner reg-prefetch at round top, interp after MFMA, ONE
// barrier/round, K=64/round) at N=64px, grid 288x512:
//  - per-block bytes 2.36MB serve 64px (was 1.77MB/32px): traffic x0.65
//  - grid 288 -> 1.125 serial passes (was 2.25): tail x0.5
//  - all 512 threads stage one cell/round (same per-thread work as v2)
//  - acc[2][4] (32 VGPR), est ~90 total, launch_bounds(512,4) cap 128
// R14's identical-shape attempt failed because its prefetches were SUNK
// (VGPR=56); v2's global_load_lds DMA is sink-proof. R18 lesson: no VGPR
// squeeze. offconv/transpose/preps unchanged from R19.
// k' = kk*256 + c. XCD swizzle: blockIdx%8 = XCD.

#define KTOT 2304
#define PXB  9216

typedef __attribute__((ext_vector_type(8))) short bf16x8;
typedef __attribute__((ext_vector_type(4))) float f32x4;

static __device__ __forceinline__ unsigned short f2bf(float f) {
    union { float f; unsigned int u; } v; v.f = f;
    unsigned int r = (v.u + 0x7FFFu + ((v.u >> 16) & 1u)) >> 16;
    return (unsigned short)r;
}
static __device__ __forceinline__ float bf2f(unsigned short h) {
    union { unsigned int u; float f; } v; v.u = ((unsigned int)h) << 16;
    return v.f;
}
// unpack 8 bf16 (uint4) -> 8 fp32; 1 bit-op per element
static __device__ __forceinline__ void unpack8(uint4 u, float* f) {
    union { unsigned int u; float f; } t;
    t.u = u.x << 16;         f[0] = t.f;
    t.u = u.x & 0xffff0000u; f[1] = t.f;
    t.u = u.y << 16;         f[2] = t.f;
    t.u = u.y & 0xffff0000u; f[3] = t.f;
    t.u = u.z << 16;         f[4] = t.f;
    t.u = u.z & 0xffff0000u; f[5] = t.f;
    t.u = u.w << 16;         f[6] = t.f;
    t.u = u.w & 0xffff0000u; f[7] = t.f;
}

// ---------------------------------------------------------------------------
// NCHW -> NHWC transpose, hi/lo bf16 outputs
// ---------------------------------------------------------------------------
__global__ __launch_bounds__(256) void transpose_kernel(const float* __restrict__ in,
                                                        unsigned short* __restrict__ outH,
                                                        unsigned short* __restrict__ outL) {
    __shared__ float tile[64][65];
    const int hw0 = blockIdx.x * 64;
    const int c0  = blockIdx.y * 64;
    const int b   = blockIdx.z;
    const int lx  = threadIdx.x & 63;
    const int ly  = threadIdx.x >> 6;
#pragma unroll
    for (int i = 0; i < 16; ++i) {
        int cl = ly + i * 4;
        tile[cl][lx] = in[(size_t)(b * 256 + c0 + cl) * PXB + hw0 + lx];
    }
    __syncthreads();
#pragma unroll
    for (int i = 0; i < 16; ++i) {
        int hwl = ly + i * 4;
        float v = tile[lx][hwl];
        size_t oi = ((size_t)b * PXB + hw0 + hwl) * 256 + c0 + lx;
        unsigned short hi = f2bf(v);
        outH[oi] = hi;
        outL[oi] = f2bf(v - bf2f(hi));
    }
}

// ---------------------------------------------------------------------------
// Main weight prep: w[o][c][kk] fp32 -> wA[o][k'=kk*256+c] bf16
// ---------------------------------------------------------------------------
__global__ __launch_bounds__(256) void prep_w_kernel(const float* __restrict__ w,
                                                     unsigned short* __restrict__ wA) {
    int idx = blockIdx.x * 256 + threadIdx.x;   // 256*2304
    int o = idx / KTOT;
    int k = idx - o * KTOT;
    int kk = k >> 8;
    int c  = k & 255;
    wA[idx] = f2bf(w[o * KTOT + c * 9 + kk]);
}

// ---------------------------------------------------------------------------
// Offset weight prep (split): rows 27..32 zero. hi = bf16(w), lo = bf16(w-hi).
// ---------------------------------------------------------------------------
__global__ __launch_bounds__(256) void prep_woff_kernel(const float* __restrict__ w,
                                                        unsigned short* __restrict__ wH,
                                                        unsigned short* __restrict__ wL) {
    int idx = blockIdx.x * 256 + threadIdx.x;   // 32*2304
    int o = idx / KTOT;
    int k = idx - o * KTOT;
    int kk = k >> 8;
    int c  = k & 255;
    float f = (o < 27) ? w[o * KTOT + c * 9 + kk] : 0.0f;
    unsigned short hi = f2bf(f);
    wH[idx] = hi;
    wL[idx] = f2bf(f - bf2f(hi));
}

// ---------------------------------------------------------------------------
// Fused offset conv: M=32(27) x N=64px x K=2304, split-bf16 3-term. (R12)
// ---------------------------------------------------------------------------
__global__ __launch_bounds__(512) void offconv_fused(const unsigned short* __restrict__ xH,
                                                     const unsigned short* __restrict__ xL,
                                                     const unsigned short* __restrict__ AH,
                                                     const unsigned short* __restrict__ AL,
                                                     const float* __restrict__ bias,
                                                     float* __restrict__ om) {
    __shared__ __attribute__((aligned(16))) unsigned short AsH[2][32 * 72];
    __shared__ __attribute__((aligned(16))) unsigned short AsL[2][32 * 72];
    __shared__ __attribute__((aligned(16))) unsigned short BsH[2][64 * 72];
    __shared__ __attribute__((aligned(16))) unsigned short BsL[2][64 * 72];

    const int tid  = threadIdx.x;
    const int kg   = tid >> 8;
    const int tl   = tid & 255;
    const int lane = tid & 63;
    const int wq   = (tid >> 6) & 3;
    const int quad = lane >> 4, l16 = lane & 15;
    const int g    = blockIdx.x;            // 288
    const int nb   = (g & 7) * 36 + (g >> 3);
    const int n0   = nb * 64;
    const int b    = n0 / PXB;
    const int hw0  = n0 - b * PXB;

    f32x4 acc[2];
#pragma unroll
    for (int mt = 0; mt < 2; ++mt) acc[mt] = (f32x4)0.0f;

    const int arow = tl >> 3, akg = tl & 7;

    uint4 pAH, pAL, pBH0, pBL0, pBH1, pBL1;
    auto pf = [&](int it) {
        const int kt = kg * 18 + it;
        const int kk = kt >> 2, c0 = (kt & 3) * 64;
        const int dy = kk / 3 - 1, dx = kk - (kk / 3) * 3 - 1;
        size_t ai = (size_t)arow * KTOT + kt * 64 + akg * 8;
        pAH = *(const uint4*)&AH[ai];
        pAL = *(const uint4*)&AL[ai];
#pragma unroll
        for (int i = 0; i < 2; ++i) {
            int task = i * 256 + tl;
            int px = task >> 3, cg = task & 7;
            int hw = hw0 + px;
            int h = hw / 96, w = hw - h * 96;
            int y = h + dy, x = w + dx;
            uint4 hv = make_uint4(0u, 0u, 0u, 0u), lv = make_uint4(0u, 0u, 0u, 0u);
            if (((unsigned)y < 96u) && ((unsigned)x < 96u)) {
                size_t bi = ((size_t)b * PXB + y * 96 + x) * 256 + c0 + cg * 8;
                hv = *(const uint4*)&xH[bi];
                lv = *(const uint4*)&xL[bi];
            }
            if (i == 0) { pBH0 = hv; pBL0 = lv; } else { pBH1 = hv; pBL1 = lv; }
        }
    };
    pf(0);

    for (int it = 0; it < 18; ++it) {
        __syncthreads();
        *(uint4*)&AsH[kg][arow * 72 + akg * 8] = pAH;
        *(uint4*)&AsL[kg][arow * 72 + akg * 8] = pAL;
        {
            int px = tl >> 3, cg = tl & 7;
            *(uint4*)&BsH[kg][px * 72 + cg * 8] = pBH0;
            *(uint4*)&BsL[kg][px * 72 + cg * 8] = pBL0;
        }
        {
            int task = 256 + tl;
            int px = task >> 3, cg = task & 7;
            *(uint4*)&BsH[kg][px * 72 + cg * 8] = pBH1;
            *(uint4*)&BsL[kg][px * 72 + cg * 8] = pBL1;
        }
        if (it < 17) pf(it + 1);
        __syncthreads();
#pragma unroll
        for (int ks = 0; ks < 2; ++ks) {
            bf16x8 ah[2], al[2], bh, bl;
#pragma unroll
            for (int mt = 0; mt < 2; ++mt) {
                ah[mt] = *(const bf16x8*)&AsH[kg][(mt * 16 + l16) * 72 + ks * 32 + quad * 8];
                al[mt] = *(const bf16x8*)&AsL[kg][(mt * 16 + l16) * 72 + ks * 32 + quad * 8];
            }
            bh = *(const bf16x8*)&BsH[kg][(wq * 16 + l16) * 72 + ks * 32 + quad * 8];
            bl = *(const bf16x8*)&BsL[kg][(wq * 16 + l16) * 72 + ks * 32 + quad * 8];
#pragma unroll
            for (int mt = 0; mt < 2; ++mt) {
                acc[mt] = __builtin_amdgcn_mfma_f32_16x16x32_bf16(ah[mt], bh, acc[mt], 0, 0, 0);
                acc[mt] = __builtin_amdgcn_mfma_f32_16x16x32_bf16(ah[mt], bl, acc[mt], 0, 0, 0);
                acc[mt] = __builtin_amdgcn_mfma_f32_16x16x32_bf16(al[mt], bh, acc[mt], 0, 0, 0);
            }
        }
    }

    float* red = (float*)BsH;
    __syncthreads();
    if (kg == 1) {
#pragma unroll
        for (int mt = 0; mt < 2; ++mt)
#pragma unroll
            for (int r = 0; r < 4; ++r)
                red[wq * 512 + mt * 256 + quad * 64 + r * 16 + l16] = acc[mt][r];
    }
    __syncthreads();
    if (kg == 0) {
#pragma unroll
        for (int mt = 0; mt < 2; ++mt)
#pragma unroll
            for (int r = 0; r < 4; ++r) {
                float v = acc[mt][r] + red[wq * 512 + mt * 256 + quad * 64 + r * 16 + l16];
                int m = mt * 16 + quad * 4 + r;
                int n = wq * 16 + l16;
                if (m < 27)
                    om[(size_t)(b * 27 + m) * PXB + hw0 + n] = v + bias[m];
            }
    }
}

// ---------------------------------------------------------------------------
// Fused deformable conv v4 (both layers): M=256 x N=64px, 36 rounds x K=64.
// Grid 288 x 512. A: single wave-private LDS buf (4KB/wave), global_load_lds
// DMA, XOR-8 source swizzle; overwrite only after own ds_reads
// (lgkmcnt(0)+sched_barrier). B: 64px x 64ch panel, double-buffered; each
// thread stages ONE cell/round (corner prefetch at round top, interp after
// MFMA). ONE __syncthreads per round. LDS 65024B.
// out_mode 0: NCHW fp32. out_mode 1: NHWC hi/lo bf16 (outH/outL).
// ---------------------------------------------------------------------------
__global__ __launch_bounds__(512, 4) void dfconv_v4(const unsigned short* __restrict__ xB,
                                                    const float* __restrict__ om,
                                                    const unsigned short* __restrict__ A,
                                                    float* __restrict__ out,
                                                    unsigned short* __restrict__ outH,
                                                    unsigned short* __restrict__ outL,
                                                    int out_mode) {
    // arena: Abuf [8 waves][4096]B @0 (32768) | Bs [2 dbuf][64*72 ushort]
    //        @32768 (18432) | goff @51200 (4608) | gwt @55808 (9216) = 65024
    __shared__ __attribute__((aligned(16))) char smem[65024];
    unsigned short* BsD  = (unsigned short*)(smem + 32768);   // ushort units
    unsigned short* goff = (unsigned short*)(smem + 51200);
    float*          gwt  = (float*)(smem + 55808);

    const int tid  = threadIdx.x;
    const int wv   = tid >> 6;
    const int lane = tid & 63;
    const int quad = lane >> 4, l16 = lane & 15;
    // XCD swizzle: g%8 = xcd owns n-blocks [xcd*36, xcd*36+36)
    const int g    = blockIdx.x;            // 288
    const int nb   = (g & 7) * 36 + (g >> 3);
    const int n0   = nb * 64;
    const int b    = n0 / PXB;
    const int hw0  = n0 - b * PXB;

    // ---- geometry: 64 px x 9 taps = 576 tasks ----
    for (int task = tid; task < 576; task += 512) {
        int px = task / 9;
        int kk = task - px * 9;
        int hw = hw0 + px;
        int h = hw / 96, w = hw - h * 96;
        const float* omp = om + (size_t)b * 27 * PXB + hw;
        float dyv = omp[(size_t)(2 * kk) * PXB];
        float dxv = omp[(size_t)(2 * kk + 1) * PXB];
        float mv  = omp[(size_t)(18 + kk) * PXB];
        float mk  = 1.0f / (1.0f + __expf(-mv));

        float ys = (float)(h + (kk / 3) - 1) + dyv;
        float xs = (float)(w + (kk - (kk / 3) * 3) - 1) + dxv;
        float fy = floorf(ys), fx = floorf(xs);
        int iy = (int)fy, ix = (int)fx;
        float wy1 = ys - fy, wx1 = xs - fx;
        float wy0 = 1.0f - wy1, wx0 = 1.0f - wx1;
        bool yv0 = (unsigned)iy < 96u, yv1 = (unsigned)(iy + 1) < 96u;
        bool xv0 = (unsigned)ix < 96u, xv1 = (unsigned)(ix + 1) < 96u;
        int y0 = min(max(iy, 0), 95),     y1 = min(max(iy + 1, 0), 95);
        int x0 = min(max(ix, 0), 95),     x1 = min(max(ix + 1, 0), 95);
        int gg = task * 4;
        goff[gg + 0] = (unsigned short)(y0 * 96 + x0);
        goff[gg + 1] = (unsigned short)(y0 * 96 + x1);
        goff[gg + 2] = (unsigned short)(y1 * 96 + x0);
        goff[gg + 3] = (unsigned short)(y1 * 96 + x1);
        gwt[gg + 0] = (yv0 && xv0) ? mk * wy0 * wx0 : 0.0f;
        gwt[gg + 1] = (yv0 && xv1) ? mk * wy0 * wx1 : 0.0f;
        gwt[gg + 2] = (yv1 && xv0) ? mk * wy1 * wx0 : 0.0f;
        gwt[gg + 3] = (yv1 && xv1) ? mk * wy1 * wx1 : 0.0f;
    }
    __syncthreads();

    // ---- staging role: one cell = 8 channels of one px (all 512 thr) ----
    const int px = tid >> 3;                // 0..63
    const int cg = tid & 7;                 // channel group
    const unsigned short* xbase = xB + (size_t)b * PXB * 256 + cg * 8;

    // A DMA lane mapping (v2 verbatim): shot s covers rows wv*32+s*8+(lane>>3);
    // granule slot lane&7 holds global granule (lane&7)^(lane>>3).
    const int arl = lane >> 3;               // 0..7
    const int akg = (lane & 7) ^ arl;        // swizzled source granule

    f32x4 acc[2][4];
#pragma unroll
    for (int mt = 0; mt < 2; ++mt)
#pragma unroll
        for (int nt = 0; nt < 4; ++nt) acc[mt][nt] = (f32x4)0.0f;

    auto dmaA = [&](int kt) {
#pragma unroll
        for (int s = 0; s < 4; ++s) {
            const unsigned short* src =
                A + (size_t)(wv * 32 + s * 8 + arl) * KTOT + kt * 64 + akg * 8;
            char* dst = smem + wv * 4096 + s * 1024;
            __builtin_amdgcn_global_load_lds(
                (const __attribute__((address_space(1))) unsigned int*)src,
                (__attribute__((address_space(3))) unsigned int*)dst, 16, 0, 0);
        }
    };

    // ---- prologue: A(0) DMA, cells kt=0 -> Bbuf0 ----
    dmaA(0);
    {
        int gg = (px * 9 + 0) * 4;          // kt=0: tap 0, c0 0
        ushort4 o4 = *(const ushort4*)&goff[gg];
        float4 wt = *(const float4*)&gwt[gg];
        uint4 u0 = *(const uint4*)(xbase + (size_t)o4.x * 256);
        uint4 u1 = *(const uint4*)(xbase + (size_t)o4.y * 256);
        uint4 u2 = *(const uint4*)(xbase + (size_t)o4.z * 256);
        uint4 u3 = *(const uint4*)(xbase + (size_t)o4.w * 256);
        float f0[8], f1[8], f2[8], f3[8];
        unpack8(u0, f0); unpack8(u1, f1); unpack8(u2, f2); unpack8(u3, f3);
        unsigned short res[8];
#pragma unroll
        for (int j = 0; j < 8; ++j)
            res[j] = f2bf(wt.x * f0[j] + wt.y * f1[j] + wt.z * f2[j] + wt.w * f3[j]);
        *(uint4*)&BsD[px * 72 + cg * 8] = *(uint4*)res;
    }
    __syncthreads();    // A(0) drained, B(0) visible

    // ---- main loop: 36 rounds, ONE barrier each ----
    for (int r = 0; r < 36; ++r) {
        const int cur = r & 1;

        // 1. issue next round's corners (max latency cover)
        uint4 cc0, cc1, cc2, cc3; float4 wt;
        if (r < 35) {
            const int ktn = r + 1, tap = ktn >> 2, c0 = (ktn & 3) * 64;
            int gg = (px * 9 + tap) * 4;
            ushort4 o4 = *(const ushort4*)&goff[gg];
            wt = *(const float4*)&gwt[gg];
            const unsigned short* cb = xbase + c0;
            cc0 = *(const uint4*)(cb + (size_t)o4.x * 256);
            cc1 = *(const uint4*)(cb + (size_t)o4.y * 256);
            cc2 = *(const uint4*)(cb + (size_t)o4.z * 256);
            cc3 = *(const uint4*)(cb + (size_t)o4.w * 256);
        }

        // 2. A-fragments: LDS -> regs (wave-private region)
        bf16x8 af00, af01, af10, af11;   // [ks][mt]
        {
            const char* Ac = smem + wv * 4096;
            const int sw0 = ((quad ^ (l16 & 7)) * 16);
            const int sw1 = (((4 + quad) ^ (l16 & 7)) * 16);
            af00 = *(const bf16x8*)(Ac + l16 * 128 + sw0);
            af01 = *(const bf16x8*)(Ac + (16 + l16) * 128 + sw0);
            af10 = *(const bf16x8*)(Ac + l16 * 128 + sw1);
            af11 = *(const bf16x8*)(Ac + (16 + l16) * 128 + sw1);
        }
        // A reads complete before overwrite; fence per rule #18
        asm volatile("s_waitcnt lgkmcnt(0)" ::: "memory");
        __builtin_amdgcn_sched_barrier(0);

        // 3. DMA A(r+1) into the SAME wave-private region (safe post-read)
        if (r < 35) dmaA(r + 1);

        // 4. MFMA: 2 ks x (2 mt x 4 nt) = 16
        {
            const unsigned short* Br = BsD + cur * 4608;
#pragma unroll
            for (int nt = 0; nt < 4; ++nt) {
                bf16x8 b0 = *(const bf16x8*)&Br[(nt * 16 + l16) * 72 + quad * 8];
                acc[0][nt] = __builtin_amdgcn_mfma_f32_16x16x32_bf16(af00, b0, acc[0][nt], 0, 0, 0);
                acc[1][nt] = __builtin_amdgcn_mfma_f32_16x16x32_bf16(af01, b0, acc[1][nt], 0, 0, 0);
            }
#pragma unroll
            for (int nt = 0; nt < 4; ++nt) {
                bf16x8 b1 = *(const bf16x8*)&Br[(nt * 16 + l16) * 72 + 32 + quad * 8];
                acc[0][nt] = __builtin_amdgcn_mfma_f32_16x16x32_bf16(af10, b1, acc[0][nt], 0, 0, 0);
                acc[1][nt] = __builtin_amdgcn_mfma_f32_16x16x32_bf16(af11, b1, acc[1][nt], 0, 0, 0);
            }
        }

        // 5. interp prefetched corners -> other B buffer
        if (r < 35) {
            unsigned short* Bw = BsD + (cur ^ 1) * 4608;
            float f0[8], f1[8], f2[8], f3[8];
            unpack8(cc0, f0); unpack8(cc1, f1); unpack8(cc2, f2); unpack8(cc3, f3);
            unsigned short res[8];
#pragma unroll
            for (int j = 0; j < 8; ++j)
                res[j] = f2bf(wt.x * f0[j] + wt.y * f1[j] + wt.z * f2[j] + wt.w * f3[j]);
            *(uint4*)&Bw[px * 72 + cg * 8] = *(uint4*)res;
        }

        __syncthreads();    // DMA drained (A(r+1) ready), B(next) visible
    }

    // ---- epilogues: tileS aliases smem ----
    float* tileS = (float*)smem;
    if (out_mode == 0) {
        // NCHW out[b][m][hw0..+63]: 4 passes of 64 m; tileS[64][68] (17.4KB)
#pragma unroll
        for (int pass = 0; pass < 4; ++pass) {
            if ((wv >> 1) == pass) {
#pragma unroll
                for (int mt = 0; mt < 2; ++mt)
#pragma unroll
                    for (int nt = 0; nt < 4; ++nt)
#pragma unroll
                        for (int rr = 0; rr < 4; ++rr) {
                            int ml = (wv & 1) * 32 + mt * 16 + quad * 4 + rr;  // 0..63
                            int n  = nt * 16 + l16;                             // 0..63
                            tileS[ml * 68 + n] = fmaxf(acc[mt][nt][rr], 0.0f);
                        }
            }
            __syncthreads();
#pragma unroll
            for (int j = 0; j < 2; ++j) {
                int idx = j * 512 + tid;          // 1024 float4s = 64m x 16q
                int row = idx >> 4, q = idx & 15;
                *(float4*)&out[(size_t)(b * 256 + pass * 64 + row) * PXB + hw0 + q * 4] =
                    *(const float4*)&tileS[row * 68 + q * 4];
            }
            __syncthreads();
        }
    } else {
        // NHWC hi/lo bf16 (outH/outL): 4 passes of 16 px; tileS[16][264]
#pragma unroll
        for (int pass = 0; pass < 4; ++pass) {
#pragma unroll
            for (int mt = 0; mt < 2; ++mt) {
                f32x4 v = acc[mt][pass];
                v[0] = fmaxf(v[0], 0.f); v[1] = fmaxf(v[1], 0.f);
                v[2] = fmaxf(v[2], 0.f); v[3] = fmaxf(v[3], 0.f);
                *(f32x4*)&tileS[l16 * 264 + wv * 32 + mt * 16 + quad * 4] = v;
            }
            __syncthreads();
#pragma unroll
            for (int j = 0; j < 2; ++j) {
                int idx = j * 512 + tid;          // 1024 float4s = 16px x 64
                int pxl = idx >> 6, ln = idx & 63;
                float4 v = *(const float4*)&tileS[pxl * 264 + ln * 4];
                size_t oi = ((size_t)b * PXB + hw0 + pass * 16 + pxl) * 256 + ln * 4;
                unsigned short hv[4], lv[4];
#pragma unroll
                for (int e = 0; e < 4; ++e) {
                    float fe = (e == 0) ? v.x : (e == 1) ? v.y : (e == 2) ? v.z : v.w;
                    hv[e] = f2bf(fe);
                    lv[e] = f2bf(fe - bf2f(hv[e]));
                }
                *(ushort4*)&outH[oi] = *(ushort4*)hv;
                *(ushort4*)&outL[oi] = *(ushort4*)lv;
            }
            __syncthreads();
        }
    }
}

// ---------------------------------------------------------------------------
extern "C" void kernel_launch(void* const* d_in, const int* in_sizes, int n_in,
                              void* d_out, int out_size, void* d_ws, size_t ws_size,
                              hipStream_t stream) {
    const float* x     = (const float*)d_in[0];
    const float* woff0 = (const float*)d_in[1];
    const float* boff0 = (const float*)d_in[2];
    const float* w0    = (const float*)d_in[3];
    const float* woff1 = (const float*)d_in[4];
    const float* boff1 = (const float*)d_in[5];
    const float* w1    = (const float*)d_in[6];
    float* out = (float*)d_out;

    char* p = (char*)d_ws;
    float* om  = (float*)p;  p += (size_t)2 * 27 * PXB * 4;               // 2.0 MB
    unsigned short* xh  = (unsigned short*)p; p += (size_t)2 * 256 * PXB * 2;  // 9.4 MB
    unsigned short* xl  = (unsigned short*)p; p += (size_t)2 * 256 * PXB * 2;  // 9.4 MB
    unsigned short* h1h = (unsigned short*)p; p += (size_t)2 * 256 * PXB * 2;  // 9.4 MB
    unsigned short* h1l = (unsigned short*)p; p += (size_t)2 * 256 * PXB * 2;  // 9.4 MB
    unsigned short* wA0 = (unsigned short*)p; p += (size_t)256 * KTOT * 2;
    unsigned short* wA1 = (unsigned short*)p; p += (size_t)256 * KTOT * 2;
    unsigned short* wH0 = (unsigned short*)p; p += (size_t)32 * KTOT * 2;
    unsigned short* wL0 = (unsigned short*)p; p += (size_t)32 * KTOT * 2;
    unsigned short* wH1 = (unsigned short*)p; p += (size_t)32 * KTOT * 2;
    unsigned short* wL1 = (unsigned short*)p; p += (size_t)32 * KTOT * 2;

    hipLaunchKernelGGL(transpose_kernel, dim3(PXB / 64, 4, 2), dim3(256), 0, stream, x, xh, xl);
    hipLaunchKernelGGL(prep_w_kernel, dim3(256 * KTOT / 256), dim3(256), 0, stream, w0, wA0);
    hipLaunchKernelGGL(prep_w_kernel, dim3(256 * KTOT / 256), dim3(256), 0, stream, w1, wA1);
    hipLaunchKernelGGL(prep_woff_kernel, dim3(32 * KTOT / 256), dim3(256), 0, stream, woff0, wH0, wL0);
    hipLaunchKernelGGL(prep_woff_kernel, dim3(32 * KTOT / 256), dim3(256), 0, stream, woff1, wH1, wL1);

    // Layer 0: x -> h1 (NHWC hi/lo bf16)
    hipLaunchKernelGGL(offconv_fused, dim3(288), dim3(512), 0, stream, xh, xl, wH0, wL0, boff0, om);
    hipLaunchKernelGGL(dfconv_v4, dim3(288), dim3(512), 0, stream, xh, om, wA0,
                       (float*)nullptr, h1h, h1l, 1);

    // Layer 1: h1 -> out (NCHW fp32)
    hipLaunchKernelGGL(offconv_fused, dim3(288), dim3(512), 0, stream, h1h, h1l, wH1, wL1, boff1, om);
    hipLaunchKernelGGL(dfconv_v4, dim3(288), dim3(512), 0, stream, h1h, om, wA1,
                       out, (unsigned short*)nullptr, (unsigned short*)nullptr, 0);
}

// Round 11
// 274.565 us; speedup vs baseline: 1.2612x; 1.1525x over previous
//
#include <hip/hip_runtime.h>
#include <cstdint>
#include <cstddef>

// DCNv2 x2 (B=2, C=O=256, H=W=96, k=3), fully fused per layer.
// R22: rounds are A-DMA-drain paced (~2500cy/32KB; v3's 2x DMA -> 2x cost)
// AND v4's grid 288 on 256 CUs had a 2x serial tail (32 CUs ran 2 blocks,
// 224 idled; makespan 2 x T_block(43.5us) = 87us). Fix the tail: N=72px
// -> grid = 18432/72 = EXACTLY 256, one block per CU, zero tail.
// MFMA N = 5 tiles of 16 (px 72..79 = permanently-zeroed LDS pad rows ->
// zero acc contribution; stores skip px>=72). Staging 576 cells/round:
// each thread one cell, tid<64 a second. No launch_bounds cap (LDS limits
// residency; avoids R18 spill). A-path identical to v4 (wave-private DMA
// single-buffer, overwrite-after-own-read). offconv/transpose/preps
// unchanged. k' = kk*256 + c. XCD swizzle: blockIdx%8 = XCD.

#define KTOT 2304
#define PXB  9216

typedef __attribute__((ext_vector_type(8))) short bf16x8;
typedef __attribute__((ext_vector_type(4))) float f32x4;

static __device__ __forceinline__ unsigned short f2bf(float f) {
    union { float f; unsigned int u; } v; v.f = f;
    unsigned int r = (v.u + 0x7FFFu + ((v.u >> 16) & 1u)) >> 16;
    return (unsigned short)r;
}
static __device__ __forceinline__ float bf2f(unsigned short h) {
    union { unsigned int u; float f; } v; v.u = ((unsigned int)h) << 16;
    return v.f;
}
// unpack 8 bf16 (uint4) -> 8 fp32; 1 bit-op per element
static __device__ __forceinline__ void unpack8(uint4 u, float* f) {
    union { unsigned int u; float f; } t;
    t.u = u.x << 16;         f[0] = t.f;
    t.u = u.x & 0xffff0000u; f[1] = t.f;
    t.u = u.y << 16;         f[2] = t.f;
    t.u = u.y & 0xffff0000u; f[3] = t.f;
    t.u = u.z << 16;         f[4] = t.f;
    t.u = u.z & 0xffff0000u; f[5] = t.f;
    t.u = u.w << 16;         f[6] = t.f;
    t.u = u.w & 0xffff0000u; f[7] = t.f;
}

// ---------------------------------------------------------------------------
// NCHW -> NHWC transpose, hi/lo bf16 outputs
// ---------------------------------------------------------------------------
__global__ __launch_bounds__(256) void transpose_kernel(const float* __restrict__ in,
                                                        unsigned short* __restrict__ outH,
                                                        unsigned short* __restrict__ outL) {
    __shared__ float tile[64][65];
    const int hw0 = blockIdx.x * 64;
    const int c0  = blockIdx.y * 64;
    const int b   = blockIdx.z;
    const int lx  = threadIdx.x & 63;
    const int ly  = threadIdx.x >> 6;
#pragma unroll
    for (int i = 0; i < 16; ++i) {
        int cl = ly + i * 4;
        tile[cl][lx] = in[(size_t)(b * 256 + c0 + cl) * PXB + hw0 + lx];
    }
    __syncthreads();
#pragma unroll
    for (int i = 0; i < 16; ++i) {
        int hwl = ly + i * 4;
        float v = tile[lx][hwl];
        size_t oi = ((size_t)b * PXB + hw0 + hwl) * 256 + c0 + lx;
        unsigned short hi = f2bf(v);
        outH[oi] = hi;
        outL[oi] = f2bf(v - bf2f(hi));
    }
}

// ---------------------------------------------------------------------------
// Main weight prep: w[o][c][kk] fp32 -> wA[o][k'=kk*256+c] bf16
// ---------------------------------------------------------------------------
__global__ __launch_bounds__(256) void prep_w_kernel(const float* __restrict__ w,
                                                     unsigned short* __restrict__ wA) {
    int idx = blockIdx.x * 256 + threadIdx.x;   // 256*2304
    int o = idx / KTOT;
    int k = idx - o * KTOT;
    int kk = k >> 8;
    int c  = k & 255;
    wA[idx] = f2bf(w[o * KTOT + c * 9 + kk]);
}

// ---------------------------------------------------------------------------
// Offset weight prep (split): rows 27..32 zero. hi = bf16(w), lo = bf16(w-hi).
// ---------------------------------------------------------------------------
__global__ __launch_bounds__(256) void prep_woff_kernel(const float* __restrict__ w,
                                                        unsigned short* __restrict__ wH,
                                                        unsigned short* __restrict__ wL) {
    int idx = blockIdx.x * 256 + threadIdx.x;   // 32*2304
    int o = idx / KTOT;
    int k = idx - o * KTOT;
    int kk = k >> 8;
    int c  = k & 255;
    float f = (o < 27) ? w[o * KTOT + c * 9 + kk] : 0.0f;
    unsigned short hi = f2bf(f);
    wH[idx] = hi;
    wL[idx] = f2bf(f - bf2f(hi));
}

// ---------------------------------------------------------------------------
// Fused offset conv: M=32(27) x N=64px x K=2304, split-bf16 3-term. (R12)
// ---------------------------------------------------------------------------
__global__ __launch_bounds__(512) void offconv_fused(const unsigned short* __restrict__ xH,
                                                     const unsigned short* __restrict__ xL,
                                                     const unsigned short* __restrict__ AH,
                                                     const unsigned short* __restrict__ AL,
                                                     const float* __restrict__ bias,
                                                     float* __restrict__ om) {
    __shared__ __attribute__((aligned(16))) unsigned short AsH[2][32 * 72];
    __shared__ __attribute__((aligned(16))) unsigned short AsL[2][32 * 72];
    __shared__ __attribute__((aligned(16))) unsigned short BsH[2][64 * 72];
    __shared__ __attribute__((aligned(16))) unsigned short BsL[2][64 * 72];

    const int tid  = threadIdx.x;
    const int kg   = tid >> 8;
    const int tl   = tid & 255;
    const int lane = tid & 63;
    const int wq   = (tid >> 6) & 3;
    const int quad = lane >> 4, l16 = lane & 15;
    const int g    = blockIdx.x;            // 288
    const int nb   = (g & 7) * 36 + (g >> 3);
    const int n0   = nb * 64;
    const int b    = n0 / PXB;
    const int hw0  = n0 - b * PXB;

    f32x4 acc[2];
#pragma unroll
    for (int mt = 0; mt < 2; ++mt) acc[mt] = (f32x4)0.0f;

    const int arow = tl >> 3, akg = tl & 7;

    uint4 pAH, pAL, pBH0, pBL0, pBH1, pBL1;
    auto pf = [&](int it) {
        const int kt = kg * 18 + it;
        const int kk = kt >> 2, c0 = (kt & 3) * 64;
        const int dy = kk / 3 - 1, dx = kk - (kk / 3) * 3 - 1;
        size_t ai = (size_t)arow * KTOT + kt * 64 + akg * 8;
        pAH = *(const uint4*)&AH[ai];
        pAL = *(const uint4*)&AL[ai];
#pragma unroll
        for (int i = 0; i < 2; ++i) {
            int task = i * 256 + tl;
            int px = task >> 3, cg = task & 7;
            int hw = hw0 + px;
            int h = hw / 96, w = hw - h * 96;
            int y = h + dy, x = w + dx;
            uint4 hv = make_uint4(0u, 0u, 0u, 0u), lv = make_uint4(0u, 0u, 0u, 0u);
            if (((unsigned)y < 96u) && ((unsigned)x < 96u)) {
                size_t bi = ((size_t)b * PXB + y * 96 + x) * 256 + c0 + cg * 8;
                hv = *(const uint4*)&xH[bi];
                lv = *(const uint4*)&xL[bi];
            }
            if (i == 0) { pBH0 = hv; pBL0 = lv; } else { pBH1 = hv; pBL1 = lv; }
        }
    };
    pf(0);

    for (int it = 0; it < 18; ++it) {
        __syncthreads();
        *(uint4*)&AsH[kg][arow * 72 + akg * 8] = pAH;
        *(uint4*)&AsL[kg][arow * 72 + akg * 8] = pAL;
        {
            int px = tl >> 3, cg = tl & 7;
            *(uint4*)&BsH[kg][px * 72 + cg * 8] = pBH0;
            *(uint4*)&BsL[kg][px * 72 + cg * 8] = pBL0;
        }
        {
            int task = 256 + tl;
            int px = task >> 3, cg = task & 7;
            *(uint4*)&BsH[kg][px * 72 + cg * 8] = pBH1;
            *(uint4*)&BsL[kg][px * 72 + cg * 8] = pBL1;
        }
        if (it < 17) pf(it + 1);
        __syncthreads();
#pragma unroll
        for (int ks = 0; ks < 2; ++ks) {
            bf16x8 ah[2], al[2], bh, bl;
#pragma unroll
            for (int mt = 0; mt < 2; ++mt) {
                ah[mt] = *(const bf16x8*)&AsH[kg][(mt * 16 + l16) * 72 + ks * 32 + quad * 8];
                al[mt] = *(const bf16x8*)&AsL[kg][(mt * 16 + l16) * 72 + ks * 32 + quad * 8];
            }
            bh = *(const bf16x8*)&BsH[kg][(wq * 16 + l16) * 72 + ks * 32 + quad * 8];
            bl = *(const bf16x8*)&BsL[kg][(wq * 16 + l16) * 72 + ks * 32 + quad * 8];
#pragma unroll
            for (int mt = 0; mt < 2; ++mt) {
                acc[mt] = __builtin_amdgcn_mfma_f32_16x16x32_bf16(ah[mt], bh, acc[mt], 0, 0, 0);
                acc[mt] = __builtin_amdgcn_mfma_f32_16x16x32_bf16(ah[mt], bl, acc[mt], 0, 0, 0);
                acc[mt] = __builtin_amdgcn_mfma_f32_16x16x32_bf16(al[mt], bh, acc[mt], 0, 0, 0);
            }
        }
    }

    float* red = (float*)BsH;
    __syncthreads();
    if (kg == 1) {
#pragma unroll
        for (int mt = 0; mt < 2; ++mt)
#pragma unroll
            for (int r = 0; r < 4; ++r)
                red[wq * 512 + mt * 256 + quad * 64 + r * 16 + l16] = acc[mt][r];
    }
    __syncthreads();
    if (kg == 0) {
#pragma unroll
        for (int mt = 0; mt < 2; ++mt)
#pragma unroll
            for (int r = 0; r < 4; ++r) {
                float v = acc[mt][r] + red[wq * 512 + mt * 256 + quad * 64 + r * 16 + l16];
                int m = mt * 16 + quad * 4 + r;
                int n = wq * 16 + l16;
                if (m < 27)
                    om[(size_t)(b * 27 + m) * PXB + hw0 + n] = v + bias[m];
            }
    }
}

// ---------------------------------------------------------------------------
// Fused deformable conv v5 (both layers): M=256 x N=72px (pad 80),
// 36 rounds x K=64, GRID = 256 (one block per CU, zero tail).
// A: single wave-private LDS buf (4KB/wave), global_load_lds DMA, XOR-8
// source swizzle; overwrite only after own ds_reads (lgkmcnt(0)+sched_bar).
// B: [2 dbuf][80px][72 ushort]; px 72..79 zeroed once (pad -> acc += 0).
// Staging 576 cells/round: all threads 1 cell, tid<64 a second.
// out_mode 0: NCHW fp32. out_mode 1: NHWC hi/lo bf16 (outH/outL).
// ---------------------------------------------------------------------------
__global__ __launch_bounds__(512) void dfconv_v5(const unsigned short* __restrict__ xB,
                                                 const float* __restrict__ om,
                                                 const unsigned short* __restrict__ A,
                                                 float* __restrict__ out,
                                                 unsigned short* __restrict__ outH,
                                                 unsigned short* __restrict__ outL,
                                                 int out_mode) {
    // arena: Abuf [8 waves][4096]B @0 (32768) | BsD 2x(80*72) ushort
    //        @32768 (23040) | goff @55808 (648*4 us = 5184) |
    //        gwt @60992 (648*4 f32 = 10368) = 71360
    __shared__ __attribute__((aligned(16))) char smem[71360];
    unsigned short* BsD  = (unsigned short*)(smem + 32768);   // ushort units
    unsigned short* goff = (unsigned short*)(smem + 55808);
    float*          gwt  = (float*)(smem + 60992);

    const int tid  = threadIdx.x;
    const int wv   = tid >> 6;
    const int lane = tid & 63;
    const int quad = lane >> 4, l16 = lane & 15;
    // XCD swizzle: g%8 = xcd owns n-blocks [xcd*32, xcd*32+32)
    const int g    = blockIdx.x;            // 256
    const int nb   = (g & 7) * 32 + (g >> 3);
    const int b    = nb >> 7;               // 9216/72 = 128 tiles per batch
    const int hw0  = (nb & 127) * 72;

    // ---- geometry: 72 px x 9 taps = 648 tasks ----
    for (int task = tid; task < 648; task += 512) {
        int px = task / 9;
        int kk = task - px * 9;
        int hw = hw0 + px;
        int h = hw / 96, w = hw - h * 96;
        const float* omp = om + (size_t)b * 27 * PXB + hw;
        float dyv = omp[(size_t)(2 * kk) * PXB];
        float dxv = omp[(size_t)(2 * kk + 1) * PXB];
        float mv  = omp[(size_t)(18 + kk) * PXB];
        float mk  = 1.0f / (1.0f + __expf(-mv));

        float ys = (float)(h + (kk / 3) - 1) + dyv;
        float xs = (float)(w + (kk - (kk / 3) * 3) - 1) + dxv;
        float fy = floorf(ys), fx = floorf(xs);
        int iy = (int)fy, ix = (int)fx;
        float wy1 = ys - fy, wx1 = xs - fx;
        float wy0 = 1.0f - wy1, wx0 = 1.0f - wx1;
        bool yv0 = (unsigned)iy < 96u, yv1 = (unsigned)(iy + 1) < 96u;
        bool xv0 = (unsigned)ix < 96u, xv1 = (unsigned)(ix + 1) < 96u;
        int y0 = min(max(iy, 0), 95),     y1 = min(max(iy + 1, 0), 95);
        int x0 = min(max(ix, 0), 95),     x1 = min(max(ix + 1, 0), 95);
        int gg = task * 4;
        goff[gg + 0] = (unsigned short)(y0 * 96 + x0);
        goff[gg + 1] = (unsigned short)(y0 * 96 + x1);
        goff[gg + 2] = (unsigned short)(y1 * 96 + x0);
        goff[gg + 3] = (unsigned short)(y1 * 96 + x1);
        gwt[gg + 0] = (yv0 && xv0) ? mk * wy0 * wx0 : 0.0f;
        gwt[gg + 1] = (yv0 && xv1) ? mk * wy0 * wx1 : 0.0f;
        gwt[gg + 2] = (yv1 && xv0) ? mk * wy1 * wx0 : 0.0f;
        gwt[gg + 3] = (yv1 && xv1) ? mk * wy1 * wx1 : 0.0f;
    }
    // ---- zero pad rows 72..79 of both B buffers (once; never rewritten) ----
    for (int i = tid; i < 576; i += 512) {       // 576 uints = 2 bufs x 8 rows x 36
        int buf = i / 288, rem = i - buf * 288;
        int row = 72 + rem / 36, col2 = (rem - (rem / 36) * 36) * 2;
        *(unsigned int*)&BsD[buf * 5760 + row * 72 + col2] = 0u;
    }
    __syncthreads();

    // ---- staging roles: cell c = px*8+cg; c0 = tid, c1 = 512+tid (tid<64) ----
    const int px  = tid >> 3;               // 0..63
    const int cg  = tid & 7;
    const int px2 = 64 + (tid >> 3);        // 64..71 (tid<64)
    const int cg2 = tid & 7;
    const unsigned short* xbase  = xB + (size_t)b * PXB * 256 + cg * 8;
    const unsigned short* xbase2 = xB + (size_t)b * PXB * 256 + cg2 * 8;

    // A DMA lane mapping (v4 verbatim): shot s covers rows wv*32+s*8+(lane>>3);
    // granule slot lane&7 holds global granule (lane&7)^(lane>>3).
    const int arl = lane >> 3;
    const int akg = (lane & 7) ^ arl;

    f32x4 acc[2][5];
#pragma unroll
    for (int mt = 0; mt < 2; ++mt)
#pragma unroll
        for (int nt = 0; nt < 5; ++nt) acc[mt][nt] = (f32x4)0.0f;

    auto dmaA = [&](int kt) {
#pragma unroll
        for (int s = 0; s < 4; ++s) {
            const unsigned short* src =
                A + (size_t)(wv * 32 + s * 8 + arl) * KTOT + kt * 64 + akg * 8;
            char* dst = smem + wv * 4096 + s * 1024;
            __builtin_amdgcn_global_load_lds(
                (const __attribute__((address_space(1))) unsigned int*)src,
                (__attribute__((address_space(3))) unsigned int*)dst, 16, 0, 0);
        }
    };

    // ---- prologue: A(0) DMA, cells kt=0 -> Bbuf0 ----
    dmaA(0);
    {
        int gg = (px * 9 + 0) * 4;          // kt=0: tap 0, c0 0
        ushort4 o4 = *(const ushort4*)&goff[gg];
        float4 wt = *(const float4*)&gwt[gg];
        uint4 u0 = *(const uint4*)(xbase + (size_t)o4.x * 256);
        uint4 u1 = *(const uint4*)(xbase + (size_t)o4.y * 256);
        uint4 u2 = *(const uint4*)(xbase + (size_t)o4.z * 256);
        uint4 u3 = *(const uint4*)(xbase + (size_t)o4.w * 256);
        float f0[8], f1[8], f2[8], f3[8];
        unpack8(u0, f0); unpack8(u1, f1); unpack8(u2, f2); unpack8(u3, f3);
        unsigned short res[8];
#pragma unroll
        for (int j = 0; j < 8; ++j)
            res[j] = f2bf(wt.x * f0[j] + wt.y * f1[j] + wt.z * f2[j] + wt.w * f3[j]);
        *(uint4*)&BsD[px * 72 + cg * 8] = *(uint4*)res;
    }
    if (tid < 64) {
        int gg = (px2 * 9 + 0) * 4;
        ushort4 o4 = *(const ushort4*)&goff[gg];
        float4 wt = *(const float4*)&gwt[gg];
        uint4 u0 = *(const uint4*)(xbase2 + (size_t)o4.x * 256);
        uint4 u1 = *(const uint4*)(xbase2 + (size_t)o4.y * 256);
        uint4 u2 = *(const uint4*)(xbase2 + (size_t)o4.z * 256);
        uint4 u3 = *(const uint4*)(xbase2 + (size_t)o4.w * 256);
        float f0[8], f1[8], f2[8], f3[8];
        unpack8(u0, f0); unpack8(u1, f1); unpack8(u2, f2); unpack8(u3, f3);
        unsigned short res[8];
#pragma unroll
        for (int j = 0; j < 8; ++j)
            res[j] = f2bf(wt.x * f0[j] + wt.y * f1[j] + wt.z * f2[j] + wt.w * f3[j]);
        *(uint4*)&BsD[px2 * 72 + cg2 * 8] = *(uint4*)res;
    }
    __syncthreads();    // A(0) drained, B(0) visible

    // ---- main loop: 36 rounds, ONE barrier each ----
    for (int r = 0; r < 36; ++r) {
        const int cur = r & 1;

        // 1. issue next round's corners (max latency cover)
        uint4 cc0, cc1, cc2, cc3; float4 wt;
        uint4 dd0, dd1, dd2, dd3; float4 wt2;
        if (r < 35) {
            const int ktn = r + 1, tap = ktn >> 2, c0 = (ktn & 3) * 64;
            {
                int gg = (px * 9 + tap) * 4;
                ushort4 o4 = *(const ushort4*)&goff[gg];
                wt = *(const float4*)&gwt[gg];
                const unsigned short* cb = xbase + c0;
                cc0 = *(const uint4*)(cb + (size_t)o4.x * 256);
                cc1 = *(const uint4*)(cb + (size_t)o4.y * 256);
                cc2 = *(const uint4*)(cb + (size_t)o4.z * 256);
                cc3 = *(const uint4*)(cb + (size_t)o4.w * 256);
            }
            if (tid < 64) {
                int gg = (px2 * 9 + tap) * 4;
                ushort4 o4 = *(const ushort4*)&goff[gg];
                wt2 = *(const float4*)&gwt[gg];
                const unsigned short* cb = xbase2 + c0;
                dd0 = *(const uint4*)(cb + (size_t)o4.x * 256);
                dd1 = *(const uint4*)(cb + (size_t)o4.y * 256);
                dd2 = *(const uint4*)(cb + (size_t)o4.z * 256);
                dd3 = *(const uint4*)(cb + (size_t)o4.w * 256);
            }
        }

        // 2. A-fragments: LDS -> regs (wave-private region)
        bf16x8 af00, af01, af10, af11;   // [ks][mt]
        {
            const char* Ac = smem + wv * 4096;
            const int sw0 = ((quad ^ (l16 & 7)) * 16);
            const int sw1 = (((4 + quad) ^ (l16 & 7)) * 16);
            af00 = *(const bf16x8*)(Ac + l16 * 128 + sw0);
            af01 = *(const bf16x8*)(Ac + (16 + l16) * 128 + sw0);
            af10 = *(const bf16x8*)(Ac + l16 * 128 + sw1);
            af11 = *(const bf16x8*)(Ac + (16 + l16) * 128 + sw1);
        }
        // A reads complete before overwrite; fence per rule #18
        asm volatile("s_waitcnt lgkmcnt(0)" ::: "memory");
        __builtin_amdgcn_sched_barrier(0);

        // 3. DMA A(r+1) into the SAME wave-private region (safe post-read)
        if (r < 35) dmaA(r + 1);

        // 4. MFMA: 2 ks x (2 mt x 5 nt) = 20
        {
            const unsigned short* Br = BsD + cur * 5760;
#pragma unroll
            for (int nt = 0; nt < 5; ++nt) {
                bf16x8 b0 = *(const bf16x8*)&Br[(nt * 16 + l16) * 72 + quad * 8];
                acc[0][nt] = __builtin_amdgcn_mfma_f32_16x16x32_bf16(af00, b0, acc[0][nt], 0, 0, 0);
                acc[1][nt] = __builtin_amdgcn_mfma_f32_16x16x32_bf16(af01, b0, acc[1][nt], 0, 0, 0);
            }
#pragma unroll
            for (int nt = 0; nt < 5; ++nt) {
                bf16x8 b1 = *(const bf16x8*)&Br[(nt * 16 + l16) * 72 + 32 + quad * 8];
                acc[0][nt] = __builtin_amdgcn_mfma_f32_16x16x32_bf16(af10, b1, acc[0][nt], 0, 0, 0);
                acc[1][nt] = __builtin_amdgcn_mfma_f32_16x16x32_bf16(af11, b1, acc[1][nt], 0, 0, 0);
            }
        }

        // 5. interp prefetched corners -> other B buffer
        if (r < 35) {
            unsigned short* Bw = BsD + (cur ^ 1) * 5760;
            {
                float f0[8], f1[8], f2[8], f3[8];
                unpack8(cc0, f0); unpack8(cc1, f1); unpack8(cc2, f2); unpack8(cc3, f3);
                unsigned short res[8];
#pragma unroll
                for (int j = 0; j < 8; ++j)
                    res[j] = f2bf(wt.x * f0[j] + wt.y * f1[j] + wt.z * f2[j] + wt.w * f3[j]);
                *(uint4*)&Bw[px * 72 + cg * 8] = *(uint4*)res;
            }
            if (tid < 64) {
                float f0[8], f1[8], f2[8], f3[8];
                unpack8(dd0, f0); unpack8(dd1, f1); unpack8(dd2, f2); unpack8(dd3, f3);
                unsigned short res[8];
#pragma unroll
                for (int j = 0; j < 8; ++j)
                    res[j] = f2bf(wt2.x * f0[j] + wt2.y * f1[j] + wt2.z * f2[j] + wt2.w * f3[j]);
                *(uint4*)&Bw[px2 * 72 + cg2 * 8] = *(uint4*)res;
            }
        }

        __syncthreads();    // DMA drained (A(r+1) ready), B(next) visible
    }

    // ---- epilogues: tileS aliases smem ----
    float* tileS = (float*)smem;
    if (out_mode == 0) {
        // NCHW out[b][m][hw0..+71]: 4 passes of 64 m; tileS[64][80] (20.5KB)
#pragma unroll
        for (int pass = 0; pass < 4; ++pass) {
            if ((wv >> 1) == pass) {
#pragma unroll
                for (int mt = 0; mt < 2; ++mt)
#pragma unroll
                    for (int nt = 0; nt < 5; ++nt)
#pragma unroll
                        for (int rr = 0; rr < 4; ++rr) {
                            int ml = (wv & 1) * 32 + mt * 16 + quad * 4 + rr;  // 0..63
                            int n  = nt * 16 + l16;                             // 0..79
                            tileS[ml * 80 + n] = fmaxf(acc[mt][nt][rr], 0.0f);
                        }
            }
            __syncthreads();
#pragma unroll
            for (int j = 0; j < 3; ++j) {
                int idx = j * 512 + tid;          // 1152 float4s = 64m x 18q
                if (idx < 1152) {
                    int row = idx / 18, q = idx - row * 18;
                    *(float4*)&out[(size_t)(b * 256 + pass * 64 + row) * PXB + hw0 + q * 4] =
                        *(const float4*)&tileS[row * 80 + q * 4];
                }
            }
            __syncthreads();
        }
    } else {
        // NHWC hi/lo bf16 (outH/outL): 5 passes of 16 px (last 8); tileS[16][264]
#pragma unroll
        for (int pass = 0; pass < 5; ++pass) {
#pragma unroll
            for (int mt = 0; mt < 2; ++mt) {
                f32x4 v = acc[mt][pass];
                v[0] = fmaxf(v[0], 0.f); v[1] = fmaxf(v[1], 0.f);
                v[2] = fmaxf(v[2], 0.f); v[3] = fmaxf(v[3], 0.f);
                *(f32x4*)&tileS[l16 * 264 + wv * 32 + mt * 16 + quad * 4] = v;
            }
            __syncthreads();
            const int cnt = (pass < 4) ? 1024 : 512;   // pass 4: px 64..71 only
#pragma unroll
            for (int j = 0; j < 2; ++j) {
                int idx = j * 512 + tid;
                if (idx < cnt) {
                    int pxl = idx >> 6, ln = idx & 63;
                    float4 v = *(const float4*)&tileS[pxl * 264 + ln * 4];
                    size_t oi = ((size_t)b * PXB + hw0 + pass * 16 + pxl) * 256 + ln * 4;
                    unsigned short hv[4], lv[4];
#pragma unroll
                    for (int e = 0; e < 4; ++e) {
                        float fe = (e == 0) ? v.x : (e == 1) ? v.y : (e == 2) ? v.z : v.w;
                        hv[e] = f2bf(fe);
                        lv[e] = f2bf(fe - bf2f(hv[e]));
                    }
                    *(ushort4*)&outH[oi] = *(ushort4*)hv;
                    *(ushort4*)&outL[oi] = *(ushort4*)lv;
                }
            }
            __syncthreads();
        }
    }
}

// ---------------------------------------------------------------------------
extern "C" void kernel_launch(void* const* d_in, const int* in_sizes, int n_in,
                              void* d_out, int out_size, void* d_ws, size_t ws_size,
                              hipStream_t stream) {
    const float* x     = (const float*)d_in[0];
    const float* woff0 = (const float*)d_in[1];
    const float* boff0 = (const float*)d_in[2];
    const float* w0    = (const float*)d_in[3];
    const float* woff1 = (const float*)d_in[4];
    const float* boff1 = (const float*)d_in[5];
    const float* w1    = (const float*)d_in[6];
    float* out = (float*)d_out;

    char* p = (char*)d_ws;
    float* om  = (float*)p;  p += (size_t)2 * 27 * PXB * 4;               // 2.0 MB
    unsigned short* xh  = (unsigned short*)p; p += (size_t)2 * 256 * PXB * 2;  // 9.4 MB
    unsigned short* xl  = (unsigned short*)p; p += (size_t)2 * 256 * PXB * 2;  // 9.4 MB
    unsigned short* h1h = (unsigned short*)p; p += (size_t)2 * 256 * PXB * 2;  // 9.4 MB
    unsigned short* h1l = (unsigned short*)p; p += (size_t)2 * 256 * PXB * 2;  // 9.4 MB
    unsigned short* wA0 = (unsigned short*)p; p += (size_t)256 * KTOT * 2;
    unsigned short* wA1 = (unsigned short*)p; p += (size_t)256 * KTOT * 2;
    unsigned short* wH0 = (unsigned short*)p; p += (size_t)32 * KTOT * 2;
    unsigned short* wL0 = (unsigned short*)p; p += (size_t)32 * KTOT * 2;
    unsigned short* wH1 = (unsigned short*)p; p += (size_t)32 * KTOT * 2;
    unsigned short* wL1 = (unsigned short*)p; p += (size_t)32 * KTOT * 2;

    hipLaunchKernelGGL(transpose_kernel, dim3(PXB / 64, 4, 2), dim3(256), 0, stream, x, xh, xl);
    hipLaunchKernelGGL(prep_w_kernel, dim3(256 * KTOT / 256), dim3(256), 0, stream, w0, wA0);
    hipLaunchKernelGGL(prep_w_kernel, dim3(256 * KTOT / 256), dim3(256), 0, stream, w1, wA1);
    hipLaunchKernelGGL(prep_woff_kernel, dim3(32 * KTOT / 256), dim3(256), 0, stream, woff0, wH0, wL0);
    hipLaunchKernelGGL(prep_woff_kernel, dim3(32 * KTOT / 256), dim3(256), 0, stream, woff1, wH1, wL1);

    // Layer 0: x -> h1 (NHWC hi/lo bf16)
    hipLaunchKernelGGL(offconv_fused, dim3(288), dim3(512), 0, stream, xh, xl, wH0, wL0, boff0, om);
    hipLaunchKernelGGL(dfconv_v5, dim3(256), dim3(512), 0, stream, xh, om, wA0,
                       (float*)nullptr, h1h, h1l, 1);

    // Layer 1: h1 -> out (NCHW fp32)
    hipLaunchKernelGGL(offconv_fused, dim3(288), dim3(512), 0, stream, h1h, h1l, wH1, wL1, boff1, om);
    hipLaunchKernelGGL(dfconv_v5, dim3(256), dim3(512), 0, stream, h1h, om, wA1,
                       out, (unsigned short*)nullptr, (unsigned short*)nullptr, 0);
}

// Round 12
// 258.056 us; speedup vs baseline: 1.3419x; 1.0640x over previous
//
#include <hip/hip_runtime.h>
#include <cstdint>
#include <cstddef>

// DCNv2 x2 (B=2, C=O=256, H=W=96, k=3), fully fused per layer.
// R23: v5's 5200cy/round == one round's loads (68KB/CU) at the ~13-20B/cy
// latency-MLP-limited rate -> the per-round __syncthreads vmcnt(0) drain
// caps MLP at one round in flight. dfconv v6 = v5 + counted-vmcnt rounds:
//  - A double-buffered per wave (2x4KB) -> no in-round overwrite fence
//  - raw s_barrier, lgkmcnt(0)-only before it (ds_write visibility)
//  - corners prefetched TWO rounds ahead (full-round latency cover)
//  - per round group G_r={C(r+2),C2,DMA(r+1)}; wait vmcnt(|G_r|) before
//    A-reads (8, wave0 12; tail 4/0). Group-granular counts are immune to
//    intra-group scheduler reorder; vmcnt is per-wave (wave-uniform branch).
// Loads span the barrier -> steady-state MLP x2. No asm loads (R15 lesson);
// only builtin barrier/DMA + asm waitcnt (proven safe R18/R19).
// offconv/transpose/preps unchanged. k' = kk*256 + c. XCD swizzle: g%8.

#define KTOT 2304
#define PXB  9216

typedef __attribute__((ext_vector_type(8))) short bf16x8;
typedef __attribute__((ext_vector_type(4))) float f32x4;

static __device__ __forceinline__ unsigned short f2bf(float f) {
    union { float f; unsigned int u; } v; v.f = f;
    unsigned int r = (v.u + 0x7FFFu + ((v.u >> 16) & 1u)) >> 16;
    return (unsigned short)r;
}
static __device__ __forceinline__ float bf2f(unsigned short h) {
    union { unsigned int u; float f; } v; v.u = ((unsigned int)h) << 16;
    return v.f;
}
// unpack 8 bf16 (uint4) -> 8 fp32; 1 bit-op per element
static __device__ __forceinline__ void unpack8(uint4 u, float* f) {
    union { unsigned int u; float f; } t;
    t.u = u.x << 16;         f[0] = t.f;
    t.u = u.x & 0xffff0000u; f[1] = t.f;
    t.u = u.y << 16;         f[2] = t.f;
    t.u = u.y & 0xffff0000u; f[3] = t.f;
    t.u = u.z << 16;         f[4] = t.f;
    t.u = u.z & 0xffff0000u; f[5] = t.f;
    t.u = u.w << 16;         f[6] = t.f;
    t.u = u.w & 0xffff0000u; f[7] = t.f;
}

// ---------------------------------------------------------------------------
// NCHW -> NHWC transpose, hi/lo bf16 outputs
// ---------------------------------------------------------------------------
__global__ __launch_bounds__(256) void transpose_kernel(const float* __restrict__ in,
                                                        unsigned short* __restrict__ outH,
                                                        unsigned short* __restrict__ outL) {
    __shared__ float tile[64][65];
    const int hw0 = blockIdx.x * 64;
    const int c0  = blockIdx.y * 64;
    const int b   = blockIdx.z;
    const int lx  = threadIdx.x & 63;
    const int ly  = threadIdx.x >> 6;
#pragma unroll
    for (int i = 0; i < 16; ++i) {
        int cl = ly + i * 4;
        tile[cl][lx] = in[(size_t)(b * 256 + c0 + cl) * PXB + hw0 + lx];
    }
    __syncthreads();
#pragma unroll
    for (int i = 0; i < 16; ++i) {
        int hwl = ly + i * 4;
        float v = tile[lx][hwl];
        size_t oi = ((size_t)b * PXB + hw0 + hwl) * 256 + c0 + lx;
        unsigned short hi = f2bf(v);
        outH[oi] = hi;
        outL[oi] = f2bf(v - bf2f(hi));
    }
}

// ---------------------------------------------------------------------------
// Main weight prep: w[o][c][kk] fp32 -> wA[o][k'=kk*256+c] bf16
// ---------------------------------------------------------------------------
__global__ __launch_bounds__(256) void prep_w_kernel(const float* __restrict__ w,
                                                     unsigned short* __restrict__ wA) {
    int idx = blockIdx.x * 256 + threadIdx.x;   // 256*2304
    int o = idx / KTOT;
    int k = idx - o * KTOT;
    int kk = k >> 8;
    int c  = k & 255;
    wA[idx] = f2bf(w[o * KTOT + c * 9 + kk]);
}

// ---------------------------------------------------------------------------
// Offset weight prep (split): rows 27..32 zero. hi = bf16(w), lo = bf16(w-hi).
// ---------------------------------------------------------------------------
__global__ __launch_bounds__(256) void prep_woff_kernel(const float* __restrict__ w,
                                                        unsigned short* __restrict__ wH,
                                                        unsigned short* __restrict__ wL) {
    int idx = blockIdx.x * 256 + threadIdx.x;   // 32*2304
    int o = idx / KTOT;
    int k = idx - o * KTOT;
    int kk = k >> 8;
    int c  = k & 255;
    float f = (o < 27) ? w[o * KTOT + c * 9 + kk] : 0.0f;
    unsigned short hi = f2bf(f);
    wH[idx] = hi;
    wL[idx] = f2bf(f - bf2f(hi));
}

// ---------------------------------------------------------------------------
// Fused offset conv: M=32(27) x N=64px x K=2304, split-bf16 3-term. (R12)
// ---------------------------------------------------------------------------
__global__ __launch_bounds__(512) void offconv_fused(const unsigned short* __restrict__ xH,
                                                     const unsigned short* __restrict__ xL,
                                                     const unsigned short* __restrict__ AH,
                                                     const unsigned short* __restrict__ AL,
                                                     const float* __restrict__ bias,
                                                     float* __restrict__ om) {
    __shared__ __attribute__((aligned(16))) unsigned short AsH[2][32 * 72];
    __shared__ __attribute__((aligned(16))) unsigned short AsL[2][32 * 72];
    __shared__ __attribute__((aligned(16))) unsigned short BsH[2][64 * 72];
    __shared__ __attribute__((aligned(16))) unsigned short BsL[2][64 * 72];

    const int tid  = threadIdx.x;
    const int kg   = tid >> 8;
    const int tl   = tid & 255;
    const int lane = tid & 63;
    const int wq   = (tid >> 6) & 3;
    const int quad = lane >> 4, l16 = lane & 15;
    const int g    = blockIdx.x;            // 288
    const int nb   = (g & 7) * 36 + (g >> 3);
    const int n0   = nb * 64;
    const int b    = n0 / PXB;
    const int hw0  = n0 - b * PXB;

    f32x4 acc[2];
#pragma unroll
    for (int mt = 0; mt < 2; ++mt) acc[mt] = (f32x4)0.0f;

    const int arow = tl >> 3, akg = tl & 7;

    uint4 pAH, pAL, pBH0, pBL0, pBH1, pBL1;
    auto pf = [&](int it) {
        const int kt = kg * 18 + it;
        const int kk = kt >> 2, c0 = (kt & 3) * 64;
        const int dy = kk / 3 - 1, dx = kk - (kk / 3) * 3 - 1;
        size_t ai = (size_t)arow * KTOT + kt * 64 + akg * 8;
        pAH = *(const uint4*)&AH[ai];
        pAL = *(const uint4*)&AL[ai];
#pragma unroll
        for (int i = 0; i < 2; ++i) {
            int task = i * 256 + tl;
            int px = task >> 3, cg = task & 7;
            int hw = hw0 + px;
            int h = hw / 96, w = hw - h * 96;
            int y = h + dy, x = w + dx;
            uint4 hv = make_uint4(0u, 0u, 0u, 0u), lv = make_uint4(0u, 0u, 0u, 0u);
            if (((unsigned)y < 96u) && ((unsigned)x < 96u)) {
                size_t bi = ((size_t)b * PXB + y * 96 + x) * 256 + c0 + cg * 8;
                hv = *(const uint4*)&xH[bi];
                lv = *(const uint4*)&xL[bi];
            }
            if (i == 0) { pBH0 = hv; pBL0 = lv; } else { pBH1 = hv; pBL1 = lv; }
        }
    };
    pf(0);

    for (int it = 0; it < 18; ++it) {
        __syncthreads();
        *(uint4*)&AsH[kg][arow * 72 + akg * 8] = pAH;
        *(uint4*)&AsL[kg][arow * 72 + akg * 8] = pAL;
        {
            int px = tl >> 3, cg = tl & 7;
            *(uint4*)&BsH[kg][px * 72 + cg * 8] = pBH0;
            *(uint4*)&BsL[kg][px * 72 + cg * 8] = pBL0;
        }
        {
            int task = 256 + tl;
            int px = task >> 3, cg = task & 7;
            *(uint4*)&BsH[kg][px * 72 + cg * 8] = pBH1;
            *(uint4*)&BsL[kg][px * 72 + cg * 8] = pBL1;
        }
        if (it < 17) pf(it + 1);
        __syncthreads();
#pragma unroll
        for (int ks = 0; ks < 2; ++ks) {
            bf16x8 ah[2], al[2], bh, bl;
#pragma unroll
            for (int mt = 0; mt < 2; ++mt) {
                ah[mt] = *(const bf16x8*)&AsH[kg][(mt * 16 + l16) * 72 + ks * 32 + quad * 8];
                al[mt] = *(const bf16x8*)&AsL[kg][(mt * 16 + l16) * 72 + ks * 32 + quad * 8];
            }
            bh = *(const bf16x8*)&BsH[kg][(wq * 16 + l16) * 72 + ks * 32 + quad * 8];
            bl = *(const bf16x8*)&BsL[kg][(wq * 16 + l16) * 72 + ks * 32 + quad * 8];
#pragma unroll
            for (int mt = 0; mt < 2; ++mt) {
                acc[mt] = __builtin_amdgcn_mfma_f32_16x16x32_bf16(ah[mt], bh, acc[mt], 0, 0, 0);
                acc[mt] = __builtin_amdgcn_mfma_f32_16x16x32_bf16(ah[mt], bl, acc[mt], 0, 0, 0);
                acc[mt] = __builtin_amdgcn_mfma_f32_16x16x32_bf16(al[mt], bh, acc[mt], 0, 0, 0);
            }
        }
    }

    float* red = (float*)BsH;
    __syncthreads();
    if (kg == 1) {
#pragma unroll
        for (int mt = 0; mt < 2; ++mt)
#pragma unroll
            for (int r = 0; r < 4; ++r)
                red[wq * 512 + mt * 256 + quad * 64 + r * 16 + l16] = acc[mt][r];
    }
    __syncthreads();
    if (kg == 0) {
#pragma unroll
        for (int mt = 0; mt < 2; ++mt)
#pragma unroll
            for (int r = 0; r < 4; ++r) {
                float v = acc[mt][r] + red[wq * 512 + mt * 256 + quad * 64 + r * 16 + l16];
                int m = mt * 16 + quad * 4 + r;
                int n = wq * 16 + l16;
                if (m < 27)
                    om[(size_t)(b * 27 + m) * PXB + hw0 + n] = v + bias[m];
            }
    }
}

// ---------------------------------------------------------------------------
// Fused deformable conv v6 (both layers): M=256 x N=72px (pad 80),
// 36 rounds x K=64, GRID = 256. Counted-vmcnt rounds: raw s_barrier,
// lgkmcnt(0)-only; A dbuf per wave; corners prefetched 2 rounds ahead;
// group wait vmcnt(8) (wave0 12; tail 4/0) before A-reads.
// out_mode 0: NCHW fp32. out_mode 1: NHWC hi/lo bf16 (outH/outL).
// ---------------------------------------------------------------------------
__global__ __launch_bounds__(512) void dfconv_v6(const unsigned short* __restrict__ xB,
                                                 const float* __restrict__ om,
                                                 const unsigned short* __restrict__ A,
                                                 float* __restrict__ out,
                                                 unsigned short* __restrict__ outH,
                                                 unsigned short* __restrict__ outL,
                                                 int out_mode) {
    // arena: Abuf [2 dbuf][8 waves][4096]B @0 (65536) |
    //        BsD 2x(80*72) ushort @65536 (23040) |
    //        goff @88576 (5184) | gwt @93760 (10368) = 104128
    __shared__ __attribute__((aligned(16))) char smem[104128];
    unsigned short* BsD  = (unsigned short*)(smem + 65536);   // ushort units
    unsigned short* goff = (unsigned short*)(smem + 88576);
    float*          gwt  = (float*)(smem + 93760);

    const int tid  = threadIdx.x;
    const int wv   = tid >> 6;
    const int lane = tid & 63;
    const int quad = lane >> 4, l16 = lane & 15;
    // XCD swizzle: g%8 = xcd owns n-blocks [xcd*32, xcd*32+32)
    const int g    = blockIdx.x;            // 256
    const int nb   = (g & 7) * 32 + (g >> 3);
    const int b    = nb >> 7;               // 128 tiles of 72px per batch
    const int hw0  = (nb & 127) * 72;

    // ---- geometry: 72 px x 9 taps = 648 tasks ----
    for (int task = tid; task < 648; task += 512) {
        int px = task / 9;
        int kk = task - px * 9;
        int hw = hw0 + px;
        int h = hw / 96, w = hw - h * 96;
        const float* omp = om + (size_t)b * 27 * PXB + hw;
        float dyv = omp[(size_t)(2 * kk) * PXB];
        float dxv = omp[(size_t)(2 * kk + 1) * PXB];
        float mv  = omp[(size_t)(18 + kk) * PXB];
        float mk  = 1.0f / (1.0f + __expf(-mv));

        float ys = (float)(h + (kk / 3) - 1) + dyv;
        float xs = (float)(w + (kk - (kk / 3) * 3) - 1) + dxv;
        float fy = floorf(ys), fx = floorf(xs);
        int iy = (int)fy, ix = (int)fx;
        float wy1 = ys - fy, wx1 = xs - fx;
        float wy0 = 1.0f - wy1, wx0 = 1.0f - wx1;
        bool yv0 = (unsigned)iy < 96u, yv1 = (unsigned)(iy + 1) < 96u;
        bool xv0 = (unsigned)ix < 96u, xv1 = (unsigned)(ix + 1) < 96u;
        int y0 = min(max(iy, 0), 95),     y1 = min(max(iy + 1, 0), 95);
        int x0 = min(max(ix, 0), 95),     x1 = min(max(ix + 1, 0), 95);
        int gg = task * 4;
        goff[gg + 0] = (unsigned short)(y0 * 96 + x0);
        goff[gg + 1] = (unsigned short)(y0 * 96 + x1);
        goff[gg + 2] = (unsigned short)(y1 * 96 + x0);
        goff[gg + 3] = (unsigned short)(y1 * 96 + x1);
        gwt[gg + 0] = (yv0 && xv0) ? mk * wy0 * wx0 : 0.0f;
        gwt[gg + 1] = (yv0 && xv1) ? mk * wy0 * wx1 : 0.0f;
        gwt[gg + 2] = (yv1 && xv0) ? mk * wy1 * wx0 : 0.0f;
        gwt[gg + 3] = (yv1 && xv1) ? mk * wy1 * wx1 : 0.0f;
    }
    // ---- zero pad rows 72..79 of both B buffers (once; never rewritten) ----
    for (int i = tid; i < 576; i += 512) {       // 576 uints = 2 bufs x 8 rows x 36
        int buf = i / 288, rem = i - buf * 288;
        int row = 72 + rem / 36, col2 = (rem - (rem / 36) * 36) * 2;
        *(unsigned int*)&BsD[buf * 5760 + row * 72 + col2] = 0u;
    }
    __syncthreads();

    // ---- staging roles: cell c0 = tid (px 0..63), c1 = 512+tid (tid<64) ----
    const int px  = tid >> 3;               // 0..63
    const int cg  = tid & 7;
    const int px2 = 64 + (tid >> 3);        // 64..71 (tid<64 = wave 0)
    const unsigned short* xbase  = xB + (size_t)b * PXB * 256 + cg * 8;

    // A DMA lane mapping: shot s covers rows wv*32+s*8+(lane>>3);
    // granule slot lane&7 holds global granule (lane&7)^(lane>>3).
    const int arl = lane >> 3;
    const int akg = (lane & 7) ^ arl;

    f32x4 acc[2][5];
#pragma unroll
    for (int mt = 0; mt < 2; ++mt)
#pragma unroll
        for (int nt = 0; nt < 5; ++nt) acc[mt][nt] = (f32x4)0.0f;

    auto dmaA = [&](int kt, int buf) {
#pragma unroll
        for (int s = 0; s < 4; ++s) {
            const unsigned short* src =
                A + (size_t)(wv * 32 + s * 8 + arl) * KTOT + kt * 64 + akg * 8;
            char* dst = smem + buf * 32768 + wv * 4096 + s * 1024;
            __builtin_amdgcn_global_load_lds(
                (const __attribute__((address_space(1))) unsigned int*)src,
                (__attribute__((address_space(3))) unsigned int*)dst, 16, 0, 0);
        }
    };
    auto loadC = [&](int kt, uint4& c0r, uint4& c1r, uint4& c2r, uint4& c3r,
                     float4& wtr, int pxl) {
        const int tap = kt >> 2, cb0 = (kt & 3) * 64;
        int gg = (pxl * 9 + tap) * 4;
        ushort4 o4 = *(const ushort4*)&goff[gg];
        wtr = *(const float4*)&gwt[gg];
        const unsigned short* cb = xbase + cb0;
        c0r = *(const uint4*)(cb + (size_t)o4.x * 256);
        c1r = *(const uint4*)(cb + (size_t)o4.y * 256);
        c2r = *(const uint4*)(cb + (size_t)o4.z * 256);
        c3r = *(const uint4*)(cb + (size_t)o4.w * 256);
    };
    auto interpC = [&](uint4 c0r, uint4 c1r, uint4 c2r, uint4 c3r, float4 wtr,
                       unsigned short* Bw, int pxl) {
        float f0[8], f1[8], f2[8], f3[8];
        unpack8(c0r, f0); unpack8(c1r, f1); unpack8(c2r, f2); unpack8(c3r, f3);
        unsigned short res[8];
#pragma unroll
        for (int j = 0; j < 8; ++j)
            res[j] = f2bf(wtr.x * f0[j] + wtr.y * f1[j] + wtr.z * f2[j] + wtr.w * f3[j]);
        *(uint4*)&Bw[pxl * 72 + cg * 8] = *(uint4*)res;
    };

    // ---- prologue: C(0), C2(0), C(1), C2(1), DMA(0); interp C(0) -> B0 ----
    uint4 cc0, cc1, cc2, cc3; float4 cwt;       // corners to interp this round
    uint4 nn0, nn1, nn2, nn3; float4 nwt;       // corners for next round
    uint4 dc0, dc1, dc2, dc3; float4 dwt;       // wave-0 2nd cell current
    uint4 dn0, dn1, dn2, dn3; float4 dnwt;      // wave-0 2nd cell next
    loadC(0, cc0, cc1, cc2, cc3, cwt, px);
    if (tid < 64) loadC(0, dc0, dc1, dc2, dc3, dwt, px2);
    loadC(1, nn0, nn1, nn2, nn3, nwt, px);
    if (tid < 64) loadC(1, dn0, dn1, dn2, dn3, dnwt, px2);
    dmaA(0, 0);
    __builtin_amdgcn_sched_barrier(0);
    if (wv == 0) { asm volatile("s_waitcnt vmcnt(12)" ::: "memory"); }
    else         { asm volatile("s_waitcnt vmcnt(8)"  ::: "memory"); }
    __builtin_amdgcn_sched_barrier(0);
    interpC(cc0, cc1, cc2, cc3, cwt, BsD, px);
    if (tid < 64) interpC(dc0, dc1, dc2, dc3, dwt, BsD, px2);
    cc0 = nn0; cc1 = nn1; cc2 = nn2; cc3 = nn3; cwt = nwt;
    if (tid < 64) { dc0 = dn0; dc1 = dn1; dc2 = dn2; dc3 = dn3; dwt = dnwt; }
    asm volatile("s_waitcnt lgkmcnt(0)" ::: "memory");
    __builtin_amdgcn_sched_barrier(0);
    __builtin_amdgcn_s_barrier();

    // ---- main loop: 36 rounds, raw barrier, counted vmcnt ----
    for (int r = 0; r < 36; ++r) {
        const int cur = r & 1;

        // 1. issue corners(r+2) (two-round-ahead prefetch)
        if (r <= 33) {
            loadC(r + 2, nn0, nn1, nn2, nn3, nwt, px);
            if (tid < 64) loadC(r + 2, dn0, dn1, dn2, dn3, dnwt, px2);
        }
        // 2. DMA A(r+1) into the other buffer
        if (r <= 34) dmaA(r + 1, cur ^ 1);

        // 3. group wait: drain G_{r-1} (contains DMA(r) and corners(r+1))
        __builtin_amdgcn_sched_barrier(0);
        if (r <= 33) {
            if (wv == 0) { asm volatile("s_waitcnt vmcnt(12)" ::: "memory"); }
            else         { asm volatile("s_waitcnt vmcnt(8)"  ::: "memory"); }
        } else if (r == 34) {
            asm volatile("s_waitcnt vmcnt(4)" ::: "memory");
        } else {
            asm volatile("s_waitcnt vmcnt(0)" ::: "memory");
        }
        __builtin_amdgcn_sched_barrier(0);

        // 4. A-fragments from abuf[cur] + MFMA with BsD[cur]
        {
            const char* Ac = smem + cur * 32768 + wv * 4096;
            const int sw0 = ((quad ^ (l16 & 7)) * 16);
            const int sw1 = (((4 + quad) ^ (l16 & 7)) * 16);
            bf16x8 af00 = *(const bf16x8*)(Ac + l16 * 128 + sw0);
            bf16x8 af01 = *(const bf16x8*)(Ac + (16 + l16) * 128 + sw0);
            bf16x8 af10 = *(const bf16x8*)(Ac + l16 * 128 + sw1);
            bf16x8 af11 = *(const bf16x8*)(Ac + (16 + l16) * 128 + sw1);
            const unsigned short* Br = BsD + cur * 5760;
#pragma unroll
            for (int nt = 0; nt < 5; ++nt) {
                bf16x8 b0 = *(const bf16x8*)&Br[(nt * 16 + l16) * 72 + quad * 8];
                acc[0][nt] = __builtin_amdgcn_mfma_f32_16x16x32_bf16(af00, b0, acc[0][nt], 0, 0, 0);
                acc[1][nt] = __builtin_amdgcn_mfma_f32_16x16x32_bf16(af01, b0, acc[1][nt], 0, 0, 0);
            }
#pragma unroll
            for (int nt = 0; nt < 5; ++nt) {
                bf16x8 b1 = *(const bf16x8*)&Br[(nt * 16 + l16) * 72 + 32 + quad * 8];
                acc[0][nt] = __builtin_amdgcn_mfma_f32_16x16x32_bf16(af10, b1, acc[0][nt], 0, 0, 0);
                acc[1][nt] = __builtin_amdgcn_mfma_f32_16x16x32_bf16(af11, b1, acc[1][nt], 0, 0, 0);
            }
        }

        // 5. interp corners(r+1) (loaded round r-1) -> BsD[cur^1]; rotate
        if (r <= 34) {
            unsigned short* Bw = BsD + (cur ^ 1) * 5760;
            interpC(cc0, cc1, cc2, cc3, cwt, Bw, px);
            if (tid < 64) interpC(dc0, dc1, dc2, dc3, dwt, Bw, px2);
            cc0 = nn0; cc1 = nn1; cc2 = nn2; cc3 = nn3; cwt = nwt;
            if (tid < 64) { dc0 = dn0; dc1 = dn1; dc2 = dn2; dc3 = dn3; dwt = dnwt; }
        }

        // 6. ds ops visible; raw barrier (NO vmcnt drain - loads span it)
        asm volatile("s_waitcnt lgkmcnt(0)" ::: "memory");
        __builtin_amdgcn_sched_barrier(0);
        __builtin_amdgcn_s_barrier();
    }

    // drain everything before LDS reuse
    asm volatile("s_waitcnt vmcnt(0) lgkmcnt(0)" ::: "memory");
    __syncthreads();

    // ---- epilogues: tileS aliases smem ----
    float* tileS = (float*)smem;
    if (out_mode == 0) {
        // NCHW out[b][m][hw0..+71]: 4 passes of 64 m; tileS[64][80]
#pragma unroll
        for (int pass = 0; pass < 4; ++pass) {
            if ((wv >> 1) == pass) {
#pragma unroll
                for (int mt = 0; mt < 2; ++mt)
#pragma unroll
                    for (int nt = 0; nt < 5; ++nt)
#pragma unroll
                        for (int rr = 0; rr < 4; ++rr) {
                            int ml = (wv & 1) * 32 + mt * 16 + quad * 4 + rr;  // 0..63
                            int n  = nt * 16 + l16;                             // 0..79
                            tileS[ml * 80 + n] = fmaxf(acc[mt][nt][rr], 0.0f);
                        }
            }
            __syncthreads();
#pragma unroll
            for (int j = 0; j < 3; ++j) {
                int idx = j * 512 + tid;          // 1152 float4s = 64m x 18q
                if (idx < 1152) {
                    int row = idx / 18, q = idx - row * 18;
                    *(float4*)&out[(size_t)(b * 256 + pass * 64 + row) * PXB + hw0 + q * 4] =
                        *(const float4*)&tileS[row * 80 + q * 4];
                }
            }
            __syncthreads();
        }
    } else {
        // NHWC hi/lo bf16 (outH/outL): 5 passes of 16 px (last 8); tileS[16][264]
#pragma unroll
        for (int pass = 0; pass < 5; ++pass) {
#pragma unroll
            for (int mt = 0; mt < 2; ++mt) {
                f32x4 v = acc[mt][pass];
                v[0] = fmaxf(v[0], 0.f); v[1] = fmaxf(v[1], 0.f);
                v[2] = fmaxf(v[2], 0.f); v[3] = fmaxf(v[3], 0.f);
                *(f32x4*)&tileS[l16 * 264 + wv * 32 + mt * 16 + quad * 4] = v;
            }
            __syncthreads();
            const int cnt = (pass < 4) ? 1024 : 512;   // pass 4: px 64..71 only
#pragma unroll
            for (int j = 0; j < 2; ++j) {
                int idx = j * 512 + tid;
                if (idx < cnt) {
                    int pxl = idx >> 6, ln = idx & 63;
                    float4 v = *(const float4*)&tileS[pxl * 264 + ln * 4];
                    size_t oi = ((size_t)b * PXB + hw0 + pass * 16 + pxl) * 256 + ln * 4;
                    unsigned short hv[4], lv[4];
#pragma unroll
                    for (int e = 0; e < 4; ++e) {
                        float fe = (e == 0) ? v.x : (e == 1) ? v.y : (e == 2) ? v.z : v.w;
                        hv[e] = f2bf(fe);
                        lv[e] = f2bf(fe - bf2f(hv[e]));
                    }
                    *(ushort4*)&outH[oi] = *(ushort4*)hv;
                    *(ushort4*)&outL[oi] = *(ushort4*)lv;
                }
            }
            __syncthreads();
        }
    }
}

// ---------------------------------------------------------------------------
extern "C" void kernel_launch(void* const* d_in, const int* in_sizes, int n_in,
                              void* d_out, int out_size, void* d_ws, size_t ws_size,
                              hipStream_t stream) {
    const float* x     = (const float*)d_in[0];
    const float* woff0 = (const float*)d_in[1];
    const float* boff0 = (const float*)d_in[2];
    const float* w0    = (const float*)d_in[3];
    const float* woff1 = (const float*)d_in[4];
    const float* boff1 = (const float*)d_in[5];
    const float* w1    = (const float*)d_in[6];
    float* out = (float*)d_out;

    char* p = (char*)d_ws;
    float* om  = (float*)p;  p += (size_t)2 * 27 * PXB * 4;               // 2.0 MB
    unsigned short* xh  = (unsigned short*)p; p += (size_t)2 * 256 * PXB * 2;  // 9.4 MB
    unsigned short* xl  = (unsigned short*)p; p += (size_t)2 * 256 * PXB * 2;  // 9.4 MB
    unsigned short* h1h = (unsigned short*)p; p += (size_t)2 * 256 * PXB * 2;  // 9.4 MB
    unsigned short* h1l = (unsigned short*)p; p += (size_t)2 * 256 * PXB * 2;  // 9.4 MB
    unsigned short* wA0 = (unsigned short*)p; p += (size_t)256 * KTOT * 2;
    unsigned short* wA1 = (unsigned short*)p; p += (size_t)256 * KTOT * 2;
    unsigned short* wH0 = (unsigned short*)p; p += (size_t)32 * KTOT * 2;
    unsigned short* wL0 = (unsigned short*)p; p += (size_t)32 * KTOT * 2;
    unsigned short* wH1 = (unsigned short*)p; p += (size_t)32 * KTOT * 2;
    unsigned short* wL1 = (unsigned short*)p; p += (size_t)32 * KTOT * 2;

    hipLaunchKernelGGL(transpose_kernel, dim3(PXB / 64, 4, 2), dim3(256), 0, stream, x, xh, xl);
    hipLaunchKernelGGL(prep_w_kernel, dim3(256 * KTOT / 256), dim3(256), 0, stream, w0, wA0);
    hipLaunchKernelGGL(prep_w_kernel, dim3(256 * KTOT / 256), dim3(256), 0, stream, w1, wA1);
    hipLaunchKernelGGL(prep_woff_kernel, dim3(32 * KTOT / 256), dim3(256), 0, stream, woff0, wH0, wL0);
    hipLaunchKernelGGL(prep_woff_kernel, dim3(32 * KTOT / 256), dim3(256), 0, stream, woff1, wH1, wL1);

    // Layer 0: x -> h1 (NHWC hi/lo bf16)
    hipLaunchKernelGGL(offconv_fused, dim3(288), dim3(512), 0, stream, xh, xl, wH0, wL0, boff0, om);
    hipLaunchKernelGGL(dfconv_v6, dim3(256), dim3(512), 0, stream, xh, om, wA0,
                       (float*)nullptr, h1h, h1l, 1);

    // Layer 1: h1 -> out (NCHW fp32)
    hipLaunchKernelGGL(offconv_fused, dim3(288), dim3(512), 0, stream, h1h, h1l, wH1, wL1, boff1, om);
    hipLaunchKernelGGL(dfconv_v6, dim3(256), dim3(512), 0, stream, h1h, om, wA1,
                       out, (unsigned short*)nullptr, (unsigned short*)nullptr, 0);
}